// Round 3
// baseline (601.417 us; speedup 1.0000x reference)
//
#include <hip/hip_runtime.h>

// TransformerDecoderLayerQaN — MI355X round 9.
// R9: (1) reuse-grouped XCD swizzle (T1): flat%8 picks XCD; all blocks
// sharing a y (attn: same (b,h) KV slice; GEMM: same A row-panel) map to ONE
// XCD -> slice becomes L2-resident, HBM fetch once (attn KV was re-fetched
// ~3x: FETCH 41MB vs 25MB ideal). (2) GEMMs switch MT=4 -> MT=2 (64x128
// tiles): grid doubles to 4 blocks/CU, 16 waves/CU — more independent DMA
// streams to cover staging latency. Same math, same epilogues.
//
// ws layout (total 61,689,856 B — same envelope):
//   qeff  f32 [10*512]   @ 0
//   p     f32 [B*NQ*T]   @ 20480
//   Acomb f32 [B*NW*48]  @ 675840
//   mixed f32 [B*NW*D]   @ 872448
//   y1    bf16 [T*B*D]   @ 2969600    (reused: fb = lin2 out)
//   qb    bf16 [T*B*D]   @ 19746816   (reused: t1 = out_proj out; hb = FFN hidden)
//   kvb   bf16 [2][B][H][S][64] @ 36524032  (K part 0, V part 1; 8.4MB)
//     post-attn reuse: opwb @36524032, l1wb @37048320, l2wb @39145472
//   ob    bf16 [T*B*D]   @ 44912640   (reused: y2 = LN2 out)
//     pre-attn reuse: ipwb bf16[1536*512] @44912640, memb bf16[4096*512] @46485504

typedef unsigned short u16;
typedef unsigned int u32;
typedef short short8_t __attribute__((ext_vector_type(8)));
typedef float f32x4 __attribute__((ext_vector_type(4)));

#define TT 2048
#define BB 8
#define SS 512
#define DD 512
#define HH 8
#define DH 64
#define DFF 2048
#define NQ 10
#define WW 16
#define NW 128
#define KVPART 2097152   // elems per K / V part: B*H*S*DH = 8*8*512*64

__device__ __forceinline__ float b2f(u16 u) {
    return __uint_as_float(((unsigned int)u) << 16);
}
__device__ __forceinline__ u16 f2b(float f) {
    unsigned int x = __float_as_uint(f);
    unsigned int r = x + 0x7FFFu + ((x >> 16) & 1u);
    return (u16)(r >> 16);
}
__device__ __forceinline__ float wave_sum(float v) {
    #pragma unroll
    for (int o = 32; o > 0; o >>= 1) v += __shfl_xor(v, o, 64);
    return v;
}
__device__ __forceinline__ float wave_max(float v) {
    #pragma unroll
    for (int o = 32; o > 0; o >>= 1) v = fmaxf(v, __shfl_xor(v, o, 64));
    return v;
}
__device__ __forceinline__ void load4(const u16* p, float* v) {
    ushort4 t = *(const ushort4*)p;
    v[0] = b2f(t.x); v[1] = b2f(t.y); v[2] = b2f(t.z); v[3] = b2f(t.w);
}
__device__ __forceinline__ void load4(const float* p, float* v) {
    float4 t = *(const float4*)p;
    v[0] = t.x; v[1] = t.y; v[2] = t.z; v[3] = t.w;
}
__device__ __forceinline__ void st1(u16* p, float v) { *p = f2b(v); }
__device__ __forceinline__ void st1(float* p, float v) { *p = v; }

// async global->LDS, 16B per lane; lds dest = wave-uniform base + lane*16
__device__ __forceinline__ void async16(const u16* g, u16* l) {
    __builtin_amdgcn_global_load_lds((const __attribute__((address_space(1))) u32*)g,
                                     (__attribute__((address_space(3))) u32*)l, 16, 0, 0);
}

// reuse-grouped XCD swizzle: flat%8 = XCD (dispatch round-robin); all gx
// col-blocks of a y-panel get the same flat%8 -> same XCD L2. Requires gy%8==0.
__device__ __forceinline__ void xcd_remap(int& bx, int& by) {
    int flat = blockIdx.y * gridDim.x + blockIdx.x;
    int xcd = flat & 7;
    int j = flat >> 3;
    by = xcd * ((int)gridDim.y >> 3) + j / (int)gridDim.x;
    bx = j % (int)gridDim.x;
}

// ---------------- f32 -> bf16 convert ----------------
__global__ __launch_bounds__(256) void cvt_kernel(const float* __restrict__ src,
                                                  u16* __restrict__ dst) {
    int i = (blockIdx.x * 256 + threadIdx.x) * 4;
    float4 v = *(const float4*)(src + i);
    ushort4 o;
    o.x = f2b(v.x); o.y = f2b(v.y); o.z = f2b(v.z); o.w = f2b(v.w);
    *(ushort4*)(dst + i) = o;
}

// ---------------- QA block (R2 verbatim) ----------------
__global__ __launch_bounds__(512) void qeff_kernel(const float* __restrict__ queries,
                                                   float* __restrict__ qeff) {
    int d = threadIdx.x;
    const float KS = 0.0055242717280199026f; // 1/(8*sqrt(512))
    for (int n = 0; n < NQ; n++) {
        float v = queries[n * DD + d];
        float ss = wave_sum(v * v);
        float norm = sqrtf(ss);
        qeff[n * DD + d] = v / (norm + 1e-6f) * KS;
    }
}

__global__ __launch_bounds__(256) void p_kernel(const float* __restrict__ x,
                                                const float* __restrict__ qeff,
                                                float* __restrict__ p) {
    __shared__ float qe[NQ * DD];
    for (int i = threadIdx.x; i < NQ * DD; i += 256) qe[i] = qeff[i];
    __syncthreads();
    int b = blockIdx.x >> 9;
    int t = ((blockIdx.x & 511) << 2) + (threadIdx.x >> 6);
    int lane = threadIdx.x & 63;
    const float* xr = x + ((size_t)t * BB + b) * DD;
    float acc[NQ];
    #pragma unroll
    for (int n = 0; n < NQ; n++) acc[n] = 0.f;
    #pragma unroll
    for (int c = 0; c < 8; c++) {
        int d = c * 64 + lane;
        float xv = xr[d];
        #pragma unroll
        for (int n = 0; n < NQ; n++) acc[n] += xv * qe[n * DD + d];
    }
    #pragma unroll
    for (int n = 0; n < NQ; n++) {
        float s = wave_sum(acc[n]);
        if (lane == 0) p[((size_t)(b * NQ + n)) * TT + t] = s;
    }
}

__global__ __launch_bounds__(256) void win_kernel(const float* __restrict__ p,
                                                  const float* __restrict__ wk,
                                                  float* __restrict__ Acomb) {
    int id = blockIdx.x * 4 + (threadIdx.x >> 6); // b*NW + m
    int b = id >> 7, m = id & 127;
    int j = threadIdx.x & 63;
    int tj = (m - 1) * WW + j;
    bool valid = (j < 48) && (tj >= 0) && (tj < TT);
    float acc = 0.f;
    for (int n = 0; n < NQ; n++) {
        float v = valid ? p[((size_t)(b * NQ + n)) * TT + tj] : -1e30f;
        float mx = wave_max(v);
        float e = valid ? __expf(v - mx) : 0.f;
        float s = wave_sum(e);
        acc += wk[n] * (e / s);
    }
    if (j < 48) Acomb[(size_t)id * 48 + j] = acc;
}

__global__ __launch_bounds__(256) void mix_kernel(const float* __restrict__ Acomb,
                                                  const float* __restrict__ x,
                                                  float* __restrict__ mixed) {
    __shared__ float As[48];
    int id = blockIdx.x;
    int b = id >> 7, m = id & 127;
    if (threadIdx.x < 48) As[threadIdx.x] = Acomb[(size_t)id * 48 + threadIdx.x];
    __syncthreads();
    int d0 = threadIdx.x, d1 = threadIdx.x + 256;
    float a0 = 0.f, a1 = 0.f;
    int tb = (m - 1) * WW;
    for (int j = 0; j < 48; j++) {
        int t = tb + j;
        if ((unsigned)t < (unsigned)TT) {
            float aj = As[j];
            const float* xr = x + ((size_t)t * BB + b) * DD;
            a0 += aj * xr[d0];
            a1 += aj * xr[d1];
        }
    }
    mixed[(size_t)id * DD + d0] = a0;
    mixed[(size_t)id * DD + d1] = a1;
}

__global__ __launch_bounds__(256) void ln_qa_kernel(const float* __restrict__ a,
                                                    const float* __restrict__ mixed,
                                                    const float* __restrict__ g,
                                                    const float* __restrict__ bt,
                                                    u16* __restrict__ out) {
    int r = blockIdx.x * 4 + (threadIdx.x >> 6); // r = t*B+b
    int lane = threadIdx.x & 63;
    int t = r >> 3, b = r & 7;
    const float* ar = a + (size_t)r * DD;
    const float* mr = mixed + ((size_t)(b * NW + (t >> 4))) * DD;
    int d0 = lane * 8;
    float av[8], mv[8], gg[8], bb[8];
    load4(ar + d0, av); load4(ar + d0 + 4, av + 4);
    load4(mr + d0, mv); load4(mr + d0 + 4, mv + 4);
    load4(g + d0, gg);  load4(g + d0 + 4, gg + 4);
    load4(bt + d0, bb); load4(bt + d0 + 4, bb + 4);
    float v[8];
    float s = 0.f, s2 = 0.f;
    #pragma unroll
    for (int u = 0; u < 8; u++) { v[u] = av[u] + mv[u]; s += v[u]; s2 += v[u] * v[u]; }
    s = wave_sum(s); s2 = wave_sum(s2);
    float mu = s * (1.f / DD);
    float var = s2 * (1.f / DD) - mu * mu;
    float rs = rsqrtf(var + 1e-5f);
    #pragma unroll
    for (int u = 0; u < 8; u++) out[(size_t)r * DD + d0 + u] = f2b((v[u] - mu) * rs * gg[u] + bb[u]);
}

template <typename OT>
__global__ __launch_bounds__(256) void ln_rows_kernel(const u16* __restrict__ a,
                                                      const u16* __restrict__ bsrc,
                                                      const float* __restrict__ g,
                                                      const float* __restrict__ bt,
                                                      OT* __restrict__ out) {
    int r = blockIdx.x * 4 + (threadIdx.x >> 6);
    int lane = threadIdx.x & 63;
    const u16* ar = a + (size_t)r * DD;
    const u16* br = bsrc + (size_t)r * DD;
    int d0 = lane * 8;
    float av[8], cv[8], gg[8], bb[8];
    load4(ar + d0, av); load4(ar + d0 + 4, av + 4);
    load4(br + d0, cv); load4(br + d0 + 4, cv + 4);
    load4(g + d0, gg);  load4(g + d0 + 4, gg + 4);
    load4(bt + d0, bb); load4(bt + d0 + 4, bb + 4);
    float v[8];
    float s = 0.f, s2 = 0.f;
    #pragma unroll
    for (int u = 0; u < 8; u++) { v[u] = av[u] + cv[u]; s += v[u]; s2 += v[u] * v[u]; }
    s = wave_sum(s); s2 = wave_sum(s2);
    float mu = s * (1.f / DD);
    float var = s2 * (1.f / DD) - mu * mu;
    float rs = rsqrtf(var + 1e-5f);
    #pragma unroll
    for (int u = 0; u < 8; u++) st1(out + (size_t)r * DD + d0 + u, (v[u] - mu) * rs * gg[u] + bb[u]);
}

// ---------------- MFMA GEMM, double-buffered global_load_lds staging ----------------
// C = act(A[M,K] @ W[N,K]^T + bias). BM = MT*32, BN=128, BK=32, 4 waves (2x2).
// Per K-step: issue next tile's DMA into buf^1, compute buf, ONE barrier.
// XCD swizzle: all gridDim.x col-blocks of an A row-panel -> same XCD L2.
// KV=1: store C head-major kvb[part][b][h][s][64] (part=col>>9, h=(col>>6)&7).
template <int RELU, int MT, int KV>
__global__ __launch_bounds__(256) void gemm_lds(const u16* __restrict__ A,
                                                const u16* __restrict__ W,
                                                const float* __restrict__ bias,
                                                u16* __restrict__ C,
                                                int M, int N, int K) {
    constexpr int BM = MT * 32;
    constexpr int NIA = BM / 64;   // A DMA insts per wave
    __shared__ u16 As[2][BM * 32];
    __shared__ u16 Bs[2][128 * 32];
    int tid = threadIdx.x;
    int w = tid >> 6, lane = tid & 63;
    int n16 = lane & 15, quad = lane >> 4;
    int bx, by;
    xcd_remap(bx, by);
    int m0 = by * BM, n0 = bx * 128;
    int wm16 = (w >> 1) * MT;       // m-block base (16-row units) for frags
    int wn = (w & 1) * 64;

    const u16* gA[NIA];
    u16* lA[NIA];
    #pragma unroll
    for (int i = 0; i < NIA; i++) {
        int s = (w * NIA + i) * 64 + lane;
        int mb = s >> 6, kseg = (s >> 4) & 3, m = s & 15;
        gA[i] = A + (size_t)(m0 + mb * 16 + m) * K + kseg * 8;
        lA[i] = &As[0][(size_t)((w * NIA + i) * 64) * 8];
    }
    const u16* gB[2];
    u16* lB[2];
    #pragma unroll
    for (int i = 0; i < 2; i++) {
        int s = (w * 2 + i) * 64 + lane;
        int nb = s >> 6, kseg = (s >> 4) & 3, n = s & 15;
        gB[i] = W + (size_t)(n0 + nb * 16 + n) * K + kseg * 8;
        lB[i] = &Bs[0][(size_t)((w * 2 + i) * 64) * 8];
    }

    f32x4 acc[MT][4];
    #pragma unroll
    for (int i = 0; i < MT; i++)
        #pragma unroll
        for (int j = 0; j < 4; j++) acc[i][j] = (f32x4){0.f, 0.f, 0.f, 0.f};

    const int nk = K >> 5;
    // prologue: stage tile 0 into buffer 0
    #pragma unroll
    for (int i = 0; i < NIA; i++) async16(gA[i], lA[i]);
    #pragma unroll
    for (int i = 0; i < 2; i++) async16(gB[i], lB[i]);
    __syncthreads();

    for (int t = 0; t < nk; t++) {
        int cur = t & 1;
        if (t + 1 < nk) {
            int nxt = cur ^ 1;
            #pragma unroll
            for (int i = 0; i < NIA; i++) async16(gA[i] + (t + 1) * 32, lA[i] + nxt * (BM * 32));
            #pragma unroll
            for (int i = 0; i < 2; i++) async16(gB[i] + (t + 1) * 32, lB[i] + nxt * 4096);
        }
        const u16* Ac = &As[cur][0];
        const u16* Bc = &Bs[cur][0];
        short8_t af[MT], bf[4];
        #pragma unroll
        for (int im = 0; im < MT; im++)
            af[im] = *(const short8_t*)(Ac + (size_t)((wm16 + im) * 64 + lane) * 8);
        #pragma unroll
        for (int in = 0; in < 4; in++)
            bf[in] = *(const short8_t*)(Bc + (size_t)(((w & 1) * 4 + in) * 64 + lane) * 8);
        #pragma unroll
        for (int im = 0; im < MT; im++)
            #pragma unroll
            for (int in = 0; in < 4; in++)
                acc[im][in] = __builtin_amdgcn_mfma_f32_16x16x32_bf16(af[im], bf[in], acc[im][in], 0, 0, 0);
        __syncthreads();   // drains next-tile DMA; all waves done reading cur
    }

    float bia[4];
    #pragma unroll
    for (int in = 0; in < 4; in++) bia[in] = bias[n0 + wn + in * 16 + n16];
    #pragma unroll
    for (int im = 0; im < MT; im++) {
        #pragma unroll
        for (int r = 0; r < 4; r++) {
            int row = m0 + (wm16 + im) * 16 + quad * 4 + r;
            #pragma unroll
            for (int in = 0; in < 4; in++) {
                float v = acc[im][in][r] + bia[in];
                if (RELU) v = fmaxf(v, 0.f);
                if (KV) {
                    int col = n0 + wn + in * 16 + n16;
                    int part = col >> 9, h = (col >> 6) & 7, d = col & 63;
                    int s = row >> 3, bq = row & 7;
                    C[(size_t)part * KVPART + ((size_t)(bq * HH + h) * SS + s) * DH + d] = f2b(v);
                } else {
                    C[(size_t)row * N + n0 + wn + in * 16 + n16] = f2b(v);
                }
            }
        }
    }
}

// ---------------- MFMA flash attention, cooperative double-buffered ----------------
// grid (T/64, B*H), 4 waves; wave w owns 16 q-rows. XCD swizzle groups all 32
// q-blocks of one (b,h) on one XCD -> its 256KB KV slice is L2-resident
// (1MB KV per XCD total), HBM-fetched once.
// K: global_load_lds in fragment order; V: cooperative register transpose
// (2-way-free bank mapping). 1-deep prefetch; per-chunk __syncthreads.
__global__ __launch_bounds__(256) void attn_wp(const u16* __restrict__ qb,
                                               const u16* __restrict__ kvb,
                                               u16* __restrict__ ob) {
    __shared__ u16 Kb[2][2048];        // fragment order, 4KB per buffer
    __shared__ u16 Vt[2][64][40];      // V^T [d][key], stride 40 (2-way free)
    __shared__ u16 Ps[4][16][40];      // per-wave P round-trip
    int tid = threadIdx.x;
    int w = tid >> 6, lane = tid & 63;
    int n16 = lane & 15, quad = lane >> 4, q8 = quad * 8;
    int xb, bh;
    xcd_remap(xb, bh);
    int b = bh >> 3, h = bh & 7;
    int q0 = xb * 64 + w * 16;

    const u16* qrow = qb + ((size_t)(q0 + n16) * BB + b) * DD + h * DH;
    short8_t aq0 = *(const short8_t*)(qrow + q8);
    short8_t aq1 = *(const short8_t*)(qrow + 32 + q8);

    const u16* kbase = kvb + (size_t)(b * HH + h) * (SS * DH);
    const u16* vbase = kvb + (size_t)KVPART + (size_t)(b * HH + h) * (SS * DH);

    // K DMA: wave w stages frag f=w (nt = w>>1, kh = w&1).
    // lane source: K[key = nt*16 + n16][d = kh*32 + quad*8 .. +8] (16B contig).
    const u16* gK = kbase + (size_t)((w >> 1) * 16 + n16) * DH + (w & 1) * 32 + q8;
    // V source: lane reads keys {kp2, kp2+1} x d [vd, vd+4) (8B each).
    int kp2 = (lane & 15) * 2;
    int vd = w * 16 + quad * 4;
    const u16* gV = vbase + (size_t)kp2 * DH + vd;

    float lsum[4];
    f32x4 Oa[4];
    #pragma unroll
    for (int r = 0; r < 4; r++) lsum[r] = 0.f;
    #pragma unroll
    for (int ot = 0; ot < 4; ot++) Oa[ot] = (f32x4){0.f, 0.f, 0.f, 0.f};

    union VU { ushort4 q; u16 h[4]; };

    // ---- stage chunk 0 ----
    {
        async16(gK, &Kb[0][w * 512]);
        VU va, vb2;
        va.q  = *(const ushort4*)(gV);
        vb2.q = *(const ushort4*)(gV + DH);
        #pragma unroll
        for (int u = 0; u < 4; u++)
            *(u32*)&Vt[0][vd + u][kp2] = (u32)va.h[u] | ((u32)vb2.h[u] << 16);
    }
    __syncthreads();

    for (int c = 0; c < 16; c++) {
        int cur = c & 1, nxt = cur ^ 1;

        // ---- prefetch chunk c+1 (issue loads; consume after compute) ----
        VU va, vb2;
        if (c < 15) {
            const u16* gVc = gV + (size_t)(c + 1) * 32 * DH;
            va.q  = *(const ushort4*)(gVc);
            vb2.q = *(const ushort4*)(gVc + DH);
            async16(gK + (size_t)(c + 1) * 32 * DH, &Kb[nxt][w * 512]);
        }

        // ---- scores S[16 q][32 keys] from Kb[cur] ----
        f32x4 sc[2];
        #pragma unroll
        for (int nt = 0; nt < 2; nt++) {
            short8_t bk0 = *(const short8_t*)&Kb[cur][(nt * 2 + 0) * 512 + lane * 8];
            short8_t bk1 = *(const short8_t*)&Kb[cur][(nt * 2 + 1) * 512 + lane * 8];
            f32x4 a = (f32x4){0.f, 0.f, 0.f, 0.f};
            a = __builtin_amdgcn_mfma_f32_16x16x32_bf16(aq0, bk0, a, 0, 0, 0);
            a = __builtin_amdgcn_mfma_f32_16x16x32_bf16(aq1, bk1, a, 0, 0, 0);
            sc[nt] = a;
        }

        // ---- fixed-max softmax: p = exp(s/8 - 8); per-lane l accumulation ----
        #pragma unroll
        for (int r = 0; r < 4; r++) {
            float p0 = __expf(sc[0][r] * 0.125f - 8.0f);
            float p1 = __expf(sc[1][r] * 0.125f - 8.0f);
            lsum[r] += p0 + p1;
            Ps[w][quad * 4 + r][n16] = f2b(p0);
            Ps[w][quad * 4 + r][16 + n16] = f2b(p1);
        }

        // ---- O += P @ V from Vt[cur] ----
        short8_t ap = *(const short8_t*)&Ps[w][n16][q8];
        #pragma unroll
        for (int ot = 0; ot < 4; ot++) {
            short8_t bv = *(const short8_t*)&Vt[cur][ot * 16 + n16][q8];
            Oa[ot] = __builtin_amdgcn_mfma_f32_16x16x32_bf16(ap, bv, Oa[ot], 0, 0, 0);
        }

        // ---- write prefetched V into Vt[nxt] ----
        if (c < 15) {
            #pragma unroll
            for (int u = 0; u < 4; u++)
                *(u32*)&Vt[nxt][vd + u][kp2] = (u32)va.h[u] | ((u32)vb2.h[u] << 16);
        }
        __syncthreads();   // drains my K-DMA (vmcnt0) + orders LDS across waves
    }

    #pragma unroll
    for (int r = 0; r < 4; r++) {
        float l = lsum[r];
        #pragma unroll
        for (int o = 1; o < 16; o <<= 1) l += __shfl_xor(l, o, 64);
        float inv = 1.f / l;
        int t = q0 + quad * 4 + r;
        u16* orow = ob + ((size_t)t * BB + b) * DD + h * DH + n16;
        #pragma unroll
        for (int ot = 0; ot < 4; ot++) orow[ot * 16] = f2b(Oa[ot][r] * inv);
    }
}

// ---------------- host ----------------
extern "C" void kernel_launch(void* const* d_in, const int* in_sizes, int n_in,
                              void* d_out, int out_size, void* d_ws, size_t ws_size,
                              hipStream_t stream) {
    const float* tgt       = (const float*)d_in[0];
    const float* memory    = (const float*)d_in[1];
    const float* queries   = (const float*)d_in[2];
    const float* wk        = (const float*)d_in[3];
    const float* in_proj_w = (const float*)d_in[4];
    const float* in_proj_b = (const float*)d_in[5];
    const float* out_proj_w= (const float*)d_in[6];
    const float* out_proj_b= (const float*)d_in[7];
    const float* lin1_w    = (const float*)d_in[8];
    const float* lin1_b    = (const float*)d_in[9];
    const float* lin2_w    = (const float*)d_in[10];
    const float* lin2_b    = (const float*)d_in[11];
    const float* ln1_g     = (const float*)d_in[12];
    const float* ln1_b     = (const float*)d_in[13];
    const float* ln2_g     = (const float*)d_in[14];
    const float* ln2_b     = (const float*)d_in[15];
    const float* ln3_g     = (const float*)d_in[16];
    const float* ln3_b     = (const float*)d_in[17];

    char* w = (char*)d_ws;
    float* qeff  = (float*)(w + 0);
    float* pbuf  = (float*)(w + 20480);
    float* Acomb = (float*)(w + 675840);
    float* mixed = (float*)(w + 872448);
    u16* y1  = (u16*)(w + 2969600);
    u16* qb  = (u16*)(w + 19746816);
    u16* kvb = (u16*)(w + 36524032);   // 8.4MB head-major KV
    u16* ob  = (u16*)(w + 44912640);
    // pre-attention residents of the ob region (dead before attn writes ob):
    u16* ipwb = (u16*)(w + 44912640);  // in_proj_w bf16 [1536*512]
    u16* memb = (u16*)(w + 46485504);  // memory bf16 [4096*512]
    // post-attention residents of the kvb region (kvb dead after attn):
    u16* opwb = (u16*)(w + 36524032);  // out_proj_w bf16 [512*512]
    u16* l1wb = (u16*)(w + 37048320);  // lin1_w bf16 [2048*512]
    u16* l2wb = (u16*)(w + 39145472);  // lin2_w bf16 [512*2048]
    u16* t1 = qb;  // out_proj result (qb dead after attention)
    u16* y2 = ob;  // LN2 out (ob = attn out, dead after out_proj)
    u16* hb = qb;  // FFN hidden chunk 4096x2048 (qb/t1 dead after LN2)
    u16* fb = y1;  // lin2 out (y1 dead after LN2)

    // ---- pre-attention weight/input conversion (into ob region) ----
    cvt_kernel<<<(SS * BB * DD) / 1024, 256, 0, stream>>>(memory, memb);
    cvt_kernel<<<(3 * DD * DD) / 1024, 256, 0, stream>>>(in_proj_w, ipwb);

    // ---- QA block ----
    qeff_kernel<<<1, 512, 0, stream>>>(queries, qeff);
    p_kernel<<<BB * (TT / 4), 256, 0, stream>>>(tgt, qeff, pbuf);
    win_kernel<<<(BB * NW) / 4, 256, 0, stream>>>(pbuf, wk, Acomb);
    mix_kernel<<<BB * NW, 256, 0, stream>>>(Acomb, tgt, mixed);
    ln_qa_kernel<<<(TT * BB) / 4, 256, 0, stream>>>(tgt, mixed, ln1_g, ln1_b, y1);

    // ---- MHA ----
    gemm_lds<0, 2, 0><<<dim3(DD / 128, (TT * BB) / 64), 256, 0, stream>>>(y1, ipwb, in_proj_b, qb, TT * BB, DD, DD);
    gemm_lds<0, 2, 1><<<dim3(1024 / 128, (SS * BB) / 64), 256, 0, stream>>>(memb, ipwb + (size_t)DD * DD, in_proj_b + DD, kvb, SS * BB, 1024, DD);
    attn_wp<<<dim3(TT / 64, BB * HH), 256, 0, stream>>>(qb, kvb, ob);
    // kvb dead; convert remaining weights into its region
    cvt_kernel<<<(DD * DD) / 1024, 256, 0, stream>>>(out_proj_w, opwb);
    cvt_kernel<<<(DFF * DD) / 1024, 256, 0, stream>>>(lin1_w, l1wb);
    cvt_kernel<<<(DD * DFF) / 1024, 256, 0, stream>>>(lin2_w, l2wb);
    gemm_lds<0, 2, 0><<<dim3(DD / 128, (TT * BB) / 64), 256, 0, stream>>>(ob, opwb, out_proj_b, t1, TT * BB, DD, DD);
    ln_rows_kernel<u16><<<(TT * BB) / 4, 256, 0, stream>>>(y1, t1, ln2_g, ln2_b, y2);

    // ---- FFN (4 chunks of 4096 rows; hidden in qb region) ----
    for (int c = 0; c < 4; c++) {
        const u16* y2c = y2 + (size_t)c * 4096 * DD;
        u16* fbc = fb + (size_t)c * 4096 * DD;
        gemm_lds<1, 2, 0><<<dim3(DFF / 128, 4096 / 64), 256, 0, stream>>>(y2c, l1wb, lin1_b, hb, 4096, DFF, DD);
        gemm_lds<0, 2, 0><<<dim3(DD / 128, 4096 / 64), 256, 0, stream>>>(hb, l2wb, lin2_b, fbc, 4096, DD, DFF);
    }
    ln_rows_kernel<float><<<(TT * BB) / 4, 256, 0, stream>>>(y2, fb, ln3_g, ln3_b, (float*)d_out);
}

// Round 4
// 577.261 us; speedup vs baseline: 1.0418x; 1.0418x over previous
//
#include <hip/hip_runtime.h>

// TransformerDecoderLayerQaN — MI355X round 10.
// R10: (1) GEMM: back to R8 tiling (MT=4; lin2 MT=2), keep XCD swizzle, and
// 2-deep software pipeline: 3 LDS buffers, stage(t+2) issued per iter,
// counted s_waitcnt vmcnt(NDMA) + raw s_barrier (loads stay in flight across
// barriers; never vmcnt(0) in main loop) — T3/T4. One barrier per K-step.
// (2) attn: 32 q-rows/wave (grid 2048->1024 blocks): 2x MFMA & softmax per
// chunk, half the KV staging and barrier events per q-row. Same KV layout
// (head-major, L2-resident per XCD — FETCH 12MB confirmed R9).
//
// ws layout (total 61,689,856 B — same envelope):
//   qeff  f32 [10*512]   @ 0
//   p     f32 [B*NQ*T]   @ 20480
//   Acomb f32 [B*NW*48]  @ 675840
//   mixed f32 [B*NW*D]   @ 872448
//   y1    bf16 [T*B*D]   @ 2969600    (reused: fb = lin2 out)
//   qb    bf16 [T*B*D]   @ 19746816   (reused: t1 = out_proj out; hb = FFN hidden)
//   kvb   bf16 [2][B][H][S][64] @ 36524032  (K part 0, V part 1; 8.4MB)
//     post-attn reuse: opwb @36524032, l1wb @37048320, l2wb @39145472
//   ob    bf16 [T*B*D]   @ 44912640   (reused: y2 = LN2 out)
//     pre-attn reuse: ipwb bf16[1536*512] @44912640, memb bf16[4096*512] @46485504

typedef unsigned short u16;
typedef unsigned int u32;
typedef short short8_t __attribute__((ext_vector_type(8)));
typedef float f32x4 __attribute__((ext_vector_type(4)));

#define TT 2048
#define BB 8
#define SS 512
#define DD 512
#define HH 8
#define DH 64
#define DFF 2048
#define NQ 10
#define WW 16
#define NW 128
#define KVPART 2097152   // elems per K / V part: B*H*S*DH = 8*8*512*64

__device__ __forceinline__ float b2f(u16 u) {
    return __uint_as_float(((unsigned int)u) << 16);
}
__device__ __forceinline__ u16 f2b(float f) {
    unsigned int x = __float_as_uint(f);
    unsigned int r = x + 0x7FFFu + ((x >> 16) & 1u);
    return (u16)(r >> 16);
}
__device__ __forceinline__ float wave_sum(float v) {
    #pragma unroll
    for (int o = 32; o > 0; o >>= 1) v += __shfl_xor(v, o, 64);
    return v;
}
__device__ __forceinline__ float wave_max(float v) {
    #pragma unroll
    for (int o = 32; o > 0; o >>= 1) v = fmaxf(v, __shfl_xor(v, o, 64));
    return v;
}
__device__ __forceinline__ void load4(const u16* p, float* v) {
    ushort4 t = *(const ushort4*)p;
    v[0] = b2f(t.x); v[1] = b2f(t.y); v[2] = b2f(t.z); v[3] = b2f(t.w);
}
__device__ __forceinline__ void load4(const float* p, float* v) {
    float4 t = *(const float4*)p;
    v[0] = t.x; v[1] = t.y; v[2] = t.z; v[3] = t.w;
}
__device__ __forceinline__ void st1(u16* p, float v) { *p = f2b(v); }
__device__ __forceinline__ void st1(float* p, float v) { *p = v; }

// async global->LDS, 16B per lane; lds dest = wave-uniform base + lane*16
__device__ __forceinline__ void async16(const u16* g, u16* l) {
    __builtin_amdgcn_global_load_lds((const __attribute__((address_space(1))) u32*)g,
                                     (__attribute__((address_space(3))) u32*)l, 16, 0, 0);
}

// reuse-grouped XCD swizzle: flat%8 = XCD (dispatch round-robin); all gx
// col-blocks of a y-panel get the same flat%8 -> same XCD L2. Requires gy%8==0.
__device__ __forceinline__ void xcd_remap(int& bx, int& by) {
    int flat = blockIdx.y * gridDim.x + blockIdx.x;
    int xcd = flat & 7;
    int j = flat >> 3;
    by = xcd * ((int)gridDim.y >> 3) + j / (int)gridDim.x;
    bx = j % (int)gridDim.x;
}

// ---------------- f32 -> bf16 convert ----------------
__global__ __launch_bounds__(256) void cvt_kernel(const float* __restrict__ src,
                                                  u16* __restrict__ dst) {
    int i = (blockIdx.x * 256 + threadIdx.x) * 4;
    float4 v = *(const float4*)(src + i);
    ushort4 o;
    o.x = f2b(v.x); o.y = f2b(v.y); o.z = f2b(v.z); o.w = f2b(v.w);
    *(ushort4*)(dst + i) = o;
}

// ---------------- QA block (R2 verbatim) ----------------
__global__ __launch_bounds__(512) void qeff_kernel(const float* __restrict__ queries,
                                                   float* __restrict__ qeff) {
    int d = threadIdx.x;
    const float KS = 0.0055242717280199026f; // 1/(8*sqrt(512))
    for (int n = 0; n < NQ; n++) {
        float v = queries[n * DD + d];
        float ss = wave_sum(v * v);
        float norm = sqrtf(ss);
        qeff[n * DD + d] = v / (norm + 1e-6f) * KS;
    }
}

__global__ __launch_bounds__(256) void p_kernel(const float* __restrict__ x,
                                                const float* __restrict__ qeff,
                                                float* __restrict__ p) {
    __shared__ float qe[NQ * DD];
    for (int i = threadIdx.x; i < NQ * DD; i += 256) qe[i] = qeff[i];
    __syncthreads();
    int b = blockIdx.x >> 9;
    int t = ((blockIdx.x & 511) << 2) + (threadIdx.x >> 6);
    int lane = threadIdx.x & 63;
    const float* xr = x + ((size_t)t * BB + b) * DD;
    float acc[NQ];
    #pragma unroll
    for (int n = 0; n < NQ; n++) acc[n] = 0.f;
    #pragma unroll
    for (int c = 0; c < 8; c++) {
        int d = c * 64 + lane;
        float xv = xr[d];
        #pragma unroll
        for (int n = 0; n < NQ; n++) acc[n] += xv * qe[n * DD + d];
    }
    #pragma unroll
    for (int n = 0; n < NQ; n++) {
        float s = wave_sum(acc[n]);
        if (lane == 0) p[((size_t)(b * NQ + n)) * TT + t] = s;
    }
}

__global__ __launch_bounds__(256) void win_kernel(const float* __restrict__ p,
                                                  const float* __restrict__ wk,
                                                  float* __restrict__ Acomb) {
    int id = blockIdx.x * 4 + (threadIdx.x >> 6); // b*NW + m
    int b = id >> 7, m = id & 127;
    int j = threadIdx.x & 63;
    int tj = (m - 1) * WW + j;
    bool valid = (j < 48) && (tj >= 0) && (tj < TT);
    float acc = 0.f;
    for (int n = 0; n < NQ; n++) {
        float v = valid ? p[((size_t)(b * NQ + n)) * TT + tj] : -1e30f;
        float mx = wave_max(v);
        float e = valid ? __expf(v - mx) : 0.f;
        float s = wave_sum(e);
        acc += wk[n] * (e / s);
    }
    if (j < 48) Acomb[(size_t)id * 48 + j] = acc;
}

__global__ __launch_bounds__(256) void mix_kernel(const float* __restrict__ Acomb,
                                                  const float* __restrict__ x,
                                                  float* __restrict__ mixed) {
    __shared__ float As[48];
    int id = blockIdx.x;
    int b = id >> 7, m = id & 127;
    if (threadIdx.x < 48) As[threadIdx.x] = Acomb[(size_t)id * 48 + threadIdx.x];
    __syncthreads();
    int d0 = threadIdx.x, d1 = threadIdx.x + 256;
    float a0 = 0.f, a1 = 0.f;
    int tb = (m - 1) * WW;
    for (int j = 0; j < 48; j++) {
        int t = tb + j;
        if ((unsigned)t < (unsigned)TT) {
            float aj = As[j];
            const float* xr = x + ((size_t)t * BB + b) * DD;
            a0 += aj * xr[d0];
            a1 += aj * xr[d1];
        }
    }
    mixed[(size_t)id * DD + d0] = a0;
    mixed[(size_t)id * DD + d1] = a1;
}

__global__ __launch_bounds__(256) void ln_qa_kernel(const float* __restrict__ a,
                                                    const float* __restrict__ mixed,
                                                    const float* __restrict__ g,
                                                    const float* __restrict__ bt,
                                                    u16* __restrict__ out) {
    int r = blockIdx.x * 4 + (threadIdx.x >> 6); // r = t*B+b
    int lane = threadIdx.x & 63;
    int t = r >> 3, b = r & 7;
    const float* ar = a + (size_t)r * DD;
    const float* mr = mixed + ((size_t)(b * NW + (t >> 4))) * DD;
    int d0 = lane * 8;
    float av[8], mv[8], gg[8], bb[8];
    load4(ar + d0, av); load4(ar + d0 + 4, av + 4);
    load4(mr + d0, mv); load4(mr + d0 + 4, mv + 4);
    load4(g + d0, gg);  load4(g + d0 + 4, gg + 4);
    load4(bt + d0, bb); load4(bt + d0 + 4, bb + 4);
    float v[8];
    float s = 0.f, s2 = 0.f;
    #pragma unroll
    for (int u = 0; u < 8; u++) { v[u] = av[u] + mv[u]; s += v[u]; s2 += v[u] * v[u]; }
    s = wave_sum(s); s2 = wave_sum(s2);
    float mu = s * (1.f / DD);
    float var = s2 * (1.f / DD) - mu * mu;
    float rs = rsqrtf(var + 1e-5f);
    #pragma unroll
    for (int u = 0; u < 8; u++) out[(size_t)r * DD + d0 + u] = f2b((v[u] - mu) * rs * gg[u] + bb[u]);
}

template <typename OT>
__global__ __launch_bounds__(256) void ln_rows_kernel(const u16* __restrict__ a,
                                                      const u16* __restrict__ bsrc,
                                                      const float* __restrict__ g,
                                                      const float* __restrict__ bt,
                                                      OT* __restrict__ out) {
    int r = blockIdx.x * 4 + (threadIdx.x >> 6);
    int lane = threadIdx.x & 63;
    const u16* ar = a + (size_t)r * DD;
    const u16* br = bsrc + (size_t)r * DD;
    int d0 = lane * 8;
    float av[8], cv[8], gg[8], bb[8];
    load4(ar + d0, av); load4(ar + d0 + 4, av + 4);
    load4(br + d0, cv); load4(br + d0 + 4, cv + 4);
    load4(g + d0, gg);  load4(g + d0 + 4, gg + 4);
    load4(bt + d0, bb); load4(bt + d0 + 4, bb + 4);
    float v[8];
    float s = 0.f, s2 = 0.f;
    #pragma unroll
    for (int u = 0; u < 8; u++) { v[u] = av[u] + cv[u]; s += v[u]; s2 += v[u] * v[u]; }
    s = wave_sum(s); s2 = wave_sum(s2);
    float mu = s * (1.f / DD);
    float var = s2 * (1.f / DD) - mu * mu;
    float rs = rsqrtf(var + 1e-5f);
    #pragma unroll
    for (int u = 0; u < 8; u++) st1(out + (size_t)r * DD + d0 + u, (v[u] - mu) * rs * gg[u] + bb[u]);
}

// ---------------- MFMA GEMM, 2-deep pipelined global_load_lds staging ----------------
// C = act(A[M,K] @ W[N,K]^T + bias). BM = MT*32, BN=128, BK=32, 4 waves (2x2).
// 3 LDS buffers; iter t: [vmcnt(NDMA) -> s_barrier] -> issue stage(t+2) ->
// compute buf[t%3] -> lgkmcnt(0). Counted vmcnt keeps t+1/t+2 loads in flight
// across the barrier (never drains to 0 in the main loop). NDMA per wave =
// NIA + 2 (A insts + B insts).
// KV=1: store C head-major kvb[part][b][h][s][64] (part=col>>9, h=(col>>6)&7).
template <int RELU, int MT, int KV>
__global__ __launch_bounds__(256) void gemm_lds(const u16* __restrict__ A,
                                                const u16* __restrict__ W,
                                                const float* __restrict__ bias,
                                                u16* __restrict__ C,
                                                int M, int N, int K) {
    constexpr int BM = MT * 32;
    constexpr int NIA = BM / 64;   // A DMA insts per wave
    __shared__ u16 As[3][BM * 32];
    __shared__ u16 Bs[3][128 * 32];
    int tid = threadIdx.x;
    int w = tid >> 6, lane = tid & 63;
    int n16 = lane & 15, quad = lane >> 4;
    int bx, by;
    xcd_remap(bx, by);
    int m0 = by * BM, n0 = bx * 128;
    int wm16 = (w >> 1) * MT;       // m-block base (16-row units) for frags
    int wn = (w & 1) * 64;

    const u16* gA[NIA];
    u16* lA[NIA];
    #pragma unroll
    for (int i = 0; i < NIA; i++) {
        int s = (w * NIA + i) * 64 + lane;
        int mb = s >> 6, kseg = (s >> 4) & 3, m = s & 15;
        gA[i] = A + (size_t)(m0 + mb * 16 + m) * K + kseg * 8;
        lA[i] = &As[0][(size_t)((w * NIA + i) * 64) * 8];
    }
    const u16* gB[2];
    u16* lB[2];
    #pragma unroll
    for (int i = 0; i < 2; i++) {
        int s = (w * 2 + i) * 64 + lane;
        int nb = s >> 6, kseg = (s >> 4) & 3, n = s & 15;
        gB[i] = W + (size_t)(n0 + nb * 16 + n) * K + kseg * 8;
        lB[i] = &Bs[0][(size_t)((w * 2 + i) * 64) * 8];
    }

    f32x4 acc[MT][4];
    #pragma unroll
    for (int i = 0; i < MT; i++)
        #pragma unroll
        for (int j = 0; j < 4; j++) acc[i][j] = (f32x4){0.f, 0.f, 0.f, 0.f};

    const int nk = K >> 5;
    // prologue: stage tiles 0,1 into buffers 0,1
    #pragma unroll
    for (int i = 0; i < NIA; i++) async16(gA[i], lA[i]);
    #pragma unroll
    for (int i = 0; i < 2; i++) async16(gB[i], lB[i]);
    #pragma unroll
    for (int i = 0; i < NIA; i++) async16(gA[i] + 32, lA[i] + BM * 32);
    #pragma unroll
    for (int i = 0; i < 2; i++) async16(gB[i] + 32, lB[i] + 4096);

    int cur = 0;
    for (int t = 0; t < nk; t++) {
        if (t + 1 < nk) {
            if constexpr (NIA + 2 == 4) {
                __asm__ volatile("s_waitcnt vmcnt(4)" ::: "memory");
            } else {
                __asm__ volatile("s_waitcnt vmcnt(3)" ::: "memory");
            }
        } else {
            __asm__ volatile("s_waitcnt vmcnt(0)" ::: "memory");
        }
        __builtin_amdgcn_s_barrier();
        __builtin_amdgcn_sched_barrier(0);
        if (t + 2 < nk) {
            int nx2 = cur + 2; if (nx2 >= 3) nx2 -= 3;
            #pragma unroll
            for (int i = 0; i < NIA; i++) async16(gA[i] + (t + 2) * 32, lA[i] + nx2 * (BM * 32));
            #pragma unroll
            for (int i = 0; i < 2; i++) async16(gB[i] + (t + 2) * 32, lB[i] + nx2 * 4096);
        }
        const u16* Ac = &As[cur][0];
        const u16* Bc = &Bs[cur][0];
        short8_t af[MT], bf[4];
        #pragma unroll
        for (int im = 0; im < MT; im++)
            af[im] = *(const short8_t*)(Ac + (size_t)((wm16 + im) * 64 + lane) * 8);
        #pragma unroll
        for (int in = 0; in < 4; in++)
            bf[in] = *(const short8_t*)(Bc + (size_t)(((w & 1) * 4 + in) * 64 + lane) * 8);
        #pragma unroll
        for (int im = 0; im < MT; im++)
            #pragma unroll
            for (int in = 0; in < 4; in++)
                acc[im][in] = __builtin_amdgcn_mfma_f32_16x16x32_bf16(af[im], bf[in], acc[im][in], 0, 0, 0);
        __asm__ volatile("s_waitcnt lgkmcnt(0)" ::: "memory");
        cur = (cur == 2) ? 0 : cur + 1;
    }

    float bia[4];
    #pragma unroll
    for (int in = 0; in < 4; in++) bia[in] = bias[n0 + wn + in * 16 + n16];
    #pragma unroll
    for (int im = 0; im < MT; im++) {
        #pragma unroll
        for (int r = 0; r < 4; r++) {
            int row = m0 + (wm16 + im) * 16 + quad * 4 + r;
            #pragma unroll
            for (int in = 0; in < 4; in++) {
                float v = acc[im][in][r] + bia[in];
                if (RELU) v = fmaxf(v, 0.f);
                if (KV) {
                    int col = n0 + wn + in * 16 + n16;
                    int part = col >> 9, h = (col >> 6) & 7, d = col & 63;
                    int s = row >> 3, bq = row & 7;
                    C[(size_t)part * KVPART + ((size_t)(bq * HH + h) * SS + s) * DH + d] = f2b(v);
                } else {
                    C[(size_t)row * N + n0 + wn + in * 16 + n16] = f2b(v);
                }
            }
        }
    }
}

// ---------------- MFMA flash attention, cooperative double-buffered ----------------
// grid (T/128, B*H), 4 waves; wave w owns 32 q-rows (2 q-tiles of 16). XCD
// swizzle groups all 16 q-blocks of one (b,h) on one XCD -> 256KB KV slice
// L2-resident (FETCH 12MB confirmed R9). Per 32-key chunk: 8 score MFMAs +
// 8 PV MFMAs per wave (2x R9) — amortizes barrier/LDS overhead per q-row.
// K: global_load_lds frag-order; V: cooperative register transpose (2-way
// free); 1-deep prefetch; per-chunk __syncthreads.
__global__ __launch_bounds__(256) void attn_wp(const u16* __restrict__ qb,
                                               const u16* __restrict__ kvb,
                                               u16* __restrict__ ob) {
    __shared__ u16 Kb[2][2048];        // fragment order, 4KB per buffer
    __shared__ u16 Vt[2][64][40];      // V^T [d][key], stride 40 (2-way free)
    __shared__ u16 Ps[4][32][40];      // per-wave P round-trip (32 q-rows)
    int tid = threadIdx.x;
    int w = tid >> 6, lane = tid & 63;
    int n16 = lane & 15, quad = lane >> 4, q8 = quad * 8;
    int xb, bh;
    xcd_remap(xb, bh);
    int b = bh >> 3, h = bh & 7;
    int q0 = xb * 128 + w * 32;

    short8_t aq[2][2];
    #pragma unroll
    for (int qt = 0; qt < 2; qt++) {
        const u16* qrow = qb + ((size_t)(q0 + qt * 16 + n16) * BB + b) * DD + h * DH;
        aq[qt][0] = *(const short8_t*)(qrow + q8);
        aq[qt][1] = *(const short8_t*)(qrow + 32 + q8);
    }

    const u16* kbase = kvb + (size_t)(b * HH + h) * (SS * DH);
    const u16* vbase = kvb + (size_t)KVPART + (size_t)(b * HH + h) * (SS * DH);

    // K DMA: wave w stages frag f=w (nt = w>>1, kh = w&1).
    const u16* gK = kbase + (size_t)((w >> 1) * 16 + n16) * DH + (w & 1) * 32 + q8;
    // V source: lane reads keys {kp2, kp2+1} x d [vd, vd+4) (8B each).
    int kp2 = (lane & 15) * 2;
    int vd = w * 16 + quad * 4;
    const u16* gV = vbase + (size_t)kp2 * DH + vd;

    float lsum[2][4];
    f32x4 Oa[2][4];
    #pragma unroll
    for (int qt = 0; qt < 2; qt++) {
        #pragma unroll
        for (int r = 0; r < 4; r++) lsum[qt][r] = 0.f;
        #pragma unroll
        for (int ot = 0; ot < 4; ot++) Oa[qt][ot] = (f32x4){0.f, 0.f, 0.f, 0.f};
    }

    union VU { ushort4 q; u16 h[4]; };

    // ---- stage chunk 0 ----
    {
        async16(gK, &Kb[0][w * 512]);
        VU va, vb2;
        va.q  = *(const ushort4*)(gV);
        vb2.q = *(const ushort4*)(gV + DH);
        #pragma unroll
        for (int u = 0; u < 4; u++)
            *(u32*)&Vt[0][vd + u][kp2] = (u32)va.h[u] | ((u32)vb2.h[u] << 16);
    }
    __syncthreads();

    for (int c = 0; c < 16; c++) {
        int cur = c & 1, nxt = cur ^ 1;

        // ---- prefetch chunk c+1 (issue loads; consume after compute) ----
        VU va, vb2;
        if (c < 15) {
            const u16* gVc = gV + (size_t)(c + 1) * 32 * DH;
            va.q  = *(const ushort4*)(gVc);
            vb2.q = *(const ushort4*)(gVc + DH);
            async16(gK + (size_t)(c + 1) * 32 * DH, &Kb[nxt][w * 512]);
        }

        // ---- scores + softmax per q-tile ----
        #pragma unroll
        for (int qt = 0; qt < 2; qt++) {
            f32x4 sc[2];
            #pragma unroll
            for (int nt = 0; nt < 2; nt++) {
                short8_t bk0 = *(const short8_t*)&Kb[cur][(nt * 2 + 0) * 512 + lane * 8];
                short8_t bk1 = *(const short8_t*)&Kb[cur][(nt * 2 + 1) * 512 + lane * 8];
                f32x4 a = (f32x4){0.f, 0.f, 0.f, 0.f};
                a = __builtin_amdgcn_mfma_f32_16x16x32_bf16(aq[qt][0], bk0, a, 0, 0, 0);
                a = __builtin_amdgcn_mfma_f32_16x16x32_bf16(aq[qt][1], bk1, a, 0, 0, 0);
                sc[nt] = a;
            }
            #pragma unroll
            for (int r = 0; r < 4; r++) {
                float p0 = __expf(sc[0][r] * 0.125f - 8.0f);
                float p1 = __expf(sc[1][r] * 0.125f - 8.0f);
                lsum[qt][r] += p0 + p1;
                Ps[w][qt * 16 + quad * 4 + r][n16] = f2b(p0);
                Ps[w][qt * 16 + quad * 4 + r][16 + n16] = f2b(p1);
            }
        }

        // ---- O += P @ V from Vt[cur] ----
        #pragma unroll
        for (int qt = 0; qt < 2; qt++) {
            short8_t ap = *(const short8_t*)&Ps[w][qt * 16 + n16][q8];
            #pragma unroll
            for (int ot = 0; ot < 4; ot++) {
                short8_t bv = *(const short8_t*)&Vt[cur][ot * 16 + n16][q8];
                Oa[qt][ot] = __builtin_amdgcn_mfma_f32_16x16x32_bf16(ap, bv, Oa[qt][ot], 0, 0, 0);
            }
        }

        // ---- write prefetched V into Vt[nxt] ----
        if (c < 15) {
            #pragma unroll
            for (int u = 0; u < 4; u++)
                *(u32*)&Vt[nxt][vd + u][kp2] = (u32)va.h[u] | ((u32)vb2.h[u] << 16);
        }
        __syncthreads();   // drains my K-DMA (vmcnt0) + orders LDS across waves
    }

    #pragma unroll
    for (int qt = 0; qt < 2; qt++) {
        #pragma unroll
        for (int r = 0; r < 4; r++) {
            float l = lsum[qt][r];
            #pragma unroll
            for (int o = 1; o < 16; o <<= 1) l += __shfl_xor(l, o, 64);
            float inv = 1.f / l;
            int t = q0 + qt * 16 + quad * 4 + r;
            u16* orow = ob + ((size_t)t * BB + b) * DD + h * DH + n16;
            #pragma unroll
            for (int ot = 0; ot < 4; ot++) orow[ot * 16] = f2b(Oa[qt][ot][r] * inv);
        }
    }
}

// ---------------- host ----------------
extern "C" void kernel_launch(void* const* d_in, const int* in_sizes, int n_in,
                              void* d_out, int out_size, void* d_ws, size_t ws_size,
                              hipStream_t stream) {
    const float* tgt       = (const float*)d_in[0];
    const float* memory    = (const float*)d_in[1];
    const float* queries   = (const float*)d_in[2];
    const float* wk        = (const float*)d_in[3];
    const float* in_proj_w = (const float*)d_in[4];
    const float* in_proj_b = (const float*)d_in[5];
    const float* out_proj_w= (const float*)d_in[6];
    const float* out_proj_b= (const float*)d_in[7];
    const float* lin1_w    = (const float*)d_in[8];
    const float* lin1_b    = (const float*)d_in[9];
    const float* lin2_w    = (const float*)d_in[10];
    const float* lin2_b    = (const float*)d_in[11];
    const float* ln1_g     = (const float*)d_in[12];
    const float* ln1_b     = (const float*)d_in[13];
    const float* ln2_g     = (const float*)d_in[14];
    const float* ln2_b     = (const float*)d_in[15];
    const float* ln3_g     = (const float*)d_in[16];
    const float* ln3_b     = (const float*)d_in[17];

    char* w = (char*)d_ws;
    float* qeff  = (float*)(w + 0);
    float* pbuf  = (float*)(w + 20480);
    float* Acomb = (float*)(w + 675840);
    float* mixed = (float*)(w + 872448);
    u16* y1  = (u16*)(w + 2969600);
    u16* qb  = (u16*)(w + 19746816);
    u16* kvb = (u16*)(w + 36524032);   // 8.4MB head-major KV
    u16* ob  = (u16*)(w + 44912640);
    // pre-attention residents of the ob region (dead before attn writes ob):
    u16* ipwb = (u16*)(w + 44912640);  // in_proj_w bf16 [1536*512]
    u16* memb = (u16*)(w + 46485504);  // memory bf16 [4096*512]
    // post-attention residents of the kvb region (kvb dead after attn):
    u16* opwb = (u16*)(w + 36524032);  // out_proj_w bf16 [512*512]
    u16* l1wb = (u16*)(w + 37048320);  // lin1_w bf16 [2048*512]
    u16* l2wb = (u16*)(w + 39145472);  // lin2_w bf16 [512*2048]
    u16* t1 = qb;  // out_proj result (qb dead after attention)
    u16* y2 = ob;  // LN2 out (ob = attn out, dead after out_proj)
    u16* hb = qb;  // FFN hidden chunk 4096x2048 (qb/t1 dead after LN2)
    u16* fb = y1;  // lin2 out (y1 dead after LN2)

    // ---- pre-attention weight/input conversion (into ob region) ----
    cvt_kernel<<<(SS * BB * DD) / 1024, 256, 0, stream>>>(memory, memb);
    cvt_kernel<<<(3 * DD * DD) / 1024, 256, 0, stream>>>(in_proj_w, ipwb);

    // ---- QA block ----
    qeff_kernel<<<1, 512, 0, stream>>>(queries, qeff);
    p_kernel<<<BB * (TT / 4), 256, 0, stream>>>(tgt, qeff, pbuf);
    win_kernel<<<(BB * NW) / 4, 256, 0, stream>>>(pbuf, wk, Acomb);
    mix_kernel<<<BB * NW, 256, 0, stream>>>(Acomb, tgt, mixed);
    ln_qa_kernel<<<(TT * BB) / 4, 256, 0, stream>>>(tgt, mixed, ln1_g, ln1_b, y1);

    // ---- MHA ----
    gemm_lds<0, 4, 0><<<dim3(DD / 128, (TT * BB) / 128), 256, 0, stream>>>(y1, ipwb, in_proj_b, qb, TT * BB, DD, DD);
    gemm_lds<0, 4, 1><<<dim3(1024 / 128, (SS * BB) / 128), 256, 0, stream>>>(memb, ipwb + (size_t)DD * DD, in_proj_b + DD, kvb, SS * BB, 1024, DD);
    attn_wp<<<dim3(TT / 128, BB * HH), 256, 0, stream>>>(qb, kvb, ob);
    // kvb dead; convert remaining weights into its region
    cvt_kernel<<<(DD * DD) / 1024, 256, 0, stream>>>(out_proj_w, opwb);
    cvt_kernel<<<(DFF * DD) / 1024, 256, 0, stream>>>(lin1_w, l1wb);
    cvt_kernel<<<(DD * DFF) / 1024, 256, 0, stream>>>(lin2_w, l2wb);
    gemm_lds<0, 4, 0><<<dim3(DD / 128, (TT * BB) / 128), 256, 0, stream>>>(ob, opwb, out_proj_b, t1, TT * BB, DD, DD);
    ln_rows_kernel<u16><<<(TT * BB) / 4, 256, 0, stream>>>(y1, t1, ln2_g, ln2_b, y2);

    // ---- FFN (4 chunks of 4096 rows; hidden in qb region) ----
    for (int c = 0; c < 4; c++) {
        const u16* y2c = y2 + (size_t)c * 4096 * DD;
        u16* fbc = fb + (size_t)c * 4096 * DD;
        gemm_lds<1, 4, 0><<<dim3(DFF / 128, 4096 / 128), 256, 0, stream>>>(y2c, l1wb, lin1_b, hb, 4096, DFF, DD);
        gemm_lds<0, 2, 0><<<dim3(DD / 128, 4096 / 64), 256, 0, stream>>>(hb, l2wb, lin2_b, fbc, 4096, DD, DFF);
    }
    ln_rows_kernel<float><<<(TT * BB) / 4, 256, 0, stream>>>(y2, fb, ln3_g, ln3_b, (float*)d_out);
}

// Round 5
// 538.613 us; speedup vs baseline: 1.1166x; 1.0718x over previous
//
#include <hip/hip_runtime.h>

// TransformerDecoderLayerQaN — MI355X round 11.
// R11: (1) GEMM reverted to R8-exact (MT4/BN128, 2-buf, 2-sync, NO swizzle —
// measured best non-attn 503us; R9/R10 swizzle+pipeline variants regressed).
// (2) attn: swapped-operand QK^T (mfma(K,Q)) -> P lives entirely in registers
// under a key-permutation sigma; V staged in sigma order (per-lane key0
// remap). Eliminates Ps LDS buffer, 16 f2b + 16 LDS stores + 2 LDS reads per
// chunk; P->bf16 via v_cvt_pk_bf16_f32 (T12). VALU/chunk ~halved.
// (3) fused cvt kernels (5->2) and win+mix -> winmix.
//
// ws layout (total 61,689,856 B — same envelope):
//   qeff  f32 [10*512]   @ 0
//   p     f32 [B*NQ*T]   @ 20480
//   Acomb (unused now)   @ 675840
//   mixed f32 [B*NW*D]   @ 872448
//   y1    bf16 [T*B*D]   @ 2969600    (reused: fb = lin2 out)
//   qb    bf16 [T*B*D]   @ 19746816   (reused: t1 = out_proj out; hb = FFN hidden)
//   kvb   bf16 [2][B][H][S][64] @ 36524032  (K part 0, V part 1; 8.4MB)
//     post-attn reuse: opwb @36524032, l1wb @37048320, l2wb @39145472
//   ob    bf16 [T*B*D]   @ 44912640   (reused: y2 = LN2 out)
//     pre-attn reuse: ipwb bf16[1536*512] @44912640, memb bf16[4096*512] @46485504

typedef unsigned short u16;
typedef unsigned int u32;
typedef short short8_t __attribute__((ext_vector_type(8)));
typedef float f32x4 __attribute__((ext_vector_type(4)));

#define TT 2048
#define BB 8
#define SS 512
#define DD 512
#define HH 8
#define DH 64
#define DFF 2048
#define NQ 10
#define WW 16
#define NW 128
#define KVPART 2097152   // elems per K / V part: B*H*S*DH = 8*8*512*64

__device__ __forceinline__ float b2f(u16 u) {
    return __uint_as_float(((unsigned int)u) << 16);
}
__device__ __forceinline__ u16 f2b(float f) {
    unsigned int x = __float_as_uint(f);
    unsigned int r = x + 0x7FFFu + ((x >> 16) & 1u);
    return (u16)(r >> 16);
}
__device__ __forceinline__ u32 cvt_pk_bf16(float lo, float hi) {
    u32 r;
    asm volatile("v_cvt_pk_bf16_f32 %0, %1, %2" : "=v"(r) : "v"(lo), "v"(hi));
    return r;
}
__device__ __forceinline__ float wave_sum(float v) {
    #pragma unroll
    for (int o = 32; o > 0; o >>= 1) v += __shfl_xor(v, o, 64);
    return v;
}
__device__ __forceinline__ float wave_max(float v) {
    #pragma unroll
    for (int o = 32; o > 0; o >>= 1) v = fmaxf(v, __shfl_xor(v, o, 64));
    return v;
}
__device__ __forceinline__ void load4(const u16* p, float* v) {
    ushort4 t = *(const ushort4*)p;
    v[0] = b2f(t.x); v[1] = b2f(t.y); v[2] = b2f(t.z); v[3] = b2f(t.w);
}
__device__ __forceinline__ void load4(const float* p, float* v) {
    float4 t = *(const float4*)p;
    v[0] = t.x; v[1] = t.y; v[2] = t.z; v[3] = t.w;
}
__device__ __forceinline__ void st1(u16* p, float v) { *p = f2b(v); }
__device__ __forceinline__ void st1(float* p, float v) { *p = v; }

// async global->LDS, 16B per lane; lds dest = wave-uniform base + lane*16
__device__ __forceinline__ void async16(const u16* g, u16* l) {
    __builtin_amdgcn_global_load_lds((const __attribute__((address_space(1))) u32*)g,
                                     (__attribute__((address_space(3))) u32*)l, 16, 0, 0);
}

// reuse-grouped XCD swizzle (attn only): flat%8 = XCD; all gx blocks of a
// y-panel -> same XCD L2. Requires gy%8==0. Proven: attn FETCH 41->12MB (R9).
__device__ __forceinline__ void xcd_remap(int& bx, int& by) {
    int flat = blockIdx.y * gridDim.x + blockIdx.x;
    int xcd = flat & 7;
    int j = flat >> 3;
    by = xcd * ((int)gridDim.y >> 3) + j / (int)gridDim.x;
    bx = j % (int)gridDim.x;
}

// ---------------- fused f32 -> bf16 converts ----------------
__device__ __forceinline__ void cvt_block(const float* s, u16* d, int base) {
    int i = base + threadIdx.x * 4;
    float4 v = *(const float4*)(s + i);
    ushort4 o;
    o.x = f2b(v.x); o.y = f2b(v.y); o.z = f2b(v.z); o.w = f2b(v.w);
    *(ushort4*)(d + i) = o;
}

// memory (2,097,152 f32 -> 2048 blocks) + in_proj_w (786,432 -> 768 blocks)
__global__ __launch_bounds__(256) void cvt2_kernel(const float* __restrict__ s0,
                                                   const float* __restrict__ s1,
                                                   u16* __restrict__ d0,
                                                   u16* __restrict__ d1) {
    int bid = blockIdx.x;
    if (bid < 2048) cvt_block(s0, d0, bid * 1024);
    else            cvt_block(s1, d1, (bid - 2048) * 1024);
}

// out_proj_w (262,144 -> 256) + lin1_w (1,048,576 -> 1024) + lin2_w (1024)
__global__ __launch_bounds__(256) void cvt3_kernel(const float* __restrict__ s0,
                                                   const float* __restrict__ s1,
                                                   const float* __restrict__ s2,
                                                   u16* __restrict__ d0,
                                                   u16* __restrict__ d1,
                                                   u16* __restrict__ d2) {
    int bid = blockIdx.x;
    if (bid < 256)       cvt_block(s0, d0, bid * 1024);
    else if (bid < 1280) cvt_block(s1, d1, (bid - 256) * 1024);
    else                 cvt_block(s2, d2, (bid - 1280) * 1024);
}

// ---------------- QA block ----------------
__global__ __launch_bounds__(512) void qeff_kernel(const float* __restrict__ queries,
                                                   float* __restrict__ qeff) {
    int d = threadIdx.x;
    const float KS = 0.0055242717280199026f; // 1/(8*sqrt(512))
    for (int n = 0; n < NQ; n++) {
        float v = queries[n * DD + d];
        float ss = wave_sum(v * v);
        float norm = sqrtf(ss);
        qeff[n * DD + d] = v / (norm + 1e-6f) * KS;
    }
}

__global__ __launch_bounds__(256) void p_kernel(const float* __restrict__ x,
                                                const float* __restrict__ qeff,
                                                float* __restrict__ p) {
    __shared__ float qe[NQ * DD];
    for (int i = threadIdx.x; i < NQ * DD; i += 256) qe[i] = qeff[i];
    __syncthreads();
    int b = blockIdx.x >> 9;
    int t = ((blockIdx.x & 511) << 2) + (threadIdx.x >> 6);
    int lane = threadIdx.x & 63;
    const float* xr = x + ((size_t)t * BB + b) * DD;
    float acc[NQ];
    #pragma unroll
    for (int n = 0; n < NQ; n++) acc[n] = 0.f;
    #pragma unroll
    for (int c = 0; c < 8; c++) {
        int d = c * 64 + lane;
        float xv = xr[d];
        #pragma unroll
        for (int n = 0; n < NQ; n++) acc[n] += xv * qe[n * DD + d];
    }
    #pragma unroll
    for (int n = 0; n < NQ; n++) {
        float s = wave_sum(acc[n]);
        if (lane == 0) p[((size_t)(b * NQ + n)) * TT + t] = s;
    }
}

// fused win + mix: wave 0 computes the 48 combined softmax weights, then all
// 256 threads do the weighted row mix. Saves a dispatch + Acomb round-trip.
__global__ __launch_bounds__(256) void winmix_kernel(const float* __restrict__ p,
                                                     const float* __restrict__ wk,
                                                     const float* __restrict__ x,
                                                     float* __restrict__ mixed) {
    __shared__ float As[48];
    int id = blockIdx.x;
    int b = id >> 7, m = id & 127;
    if (threadIdx.x < 64) {
        int j = threadIdx.x;
        int tj = (m - 1) * WW + j;
        bool valid = (j < 48) && (tj >= 0) && (tj < TT);
        float acc = 0.f;
        for (int n = 0; n < NQ; n++) {
            float v = valid ? p[((size_t)(b * NQ + n)) * TT + tj] : -1e30f;
            float mx = wave_max(v);
            float e = valid ? __expf(v - mx) : 0.f;
            float s = wave_sum(e);
            acc += wk[n] * (e / s);
        }
        if (j < 48) As[j] = acc;
    }
    __syncthreads();
    int d0 = threadIdx.x, d1 = threadIdx.x + 256;
    float a0 = 0.f, a1 = 0.f;
    int tb = (m - 1) * WW;
    for (int j = 0; j < 48; j++) {
        int t = tb + j;
        if ((unsigned)t < (unsigned)TT) {
            float aj = As[j];
            const float* xr = x + ((size_t)t * BB + b) * DD;
            a0 += aj * xr[d0];
            a1 += aj * xr[d1];
        }
    }
    mixed[(size_t)id * DD + d0] = a0;
    mixed[(size_t)id * DD + d1] = a1;
}

__global__ __launch_bounds__(256) void ln_qa_kernel(const float* __restrict__ a,
                                                    const float* __restrict__ mixed,
                                                    const float* __restrict__ g,
                                                    const float* __restrict__ bt,
                                                    u16* __restrict__ out) {
    int r = blockIdx.x * 4 + (threadIdx.x >> 6); // r = t*B+b
    int lane = threadIdx.x & 63;
    int t = r >> 3, b = r & 7;
    const float* ar = a + (size_t)r * DD;
    const float* mr = mixed + ((size_t)(b * NW + (t >> 4))) * DD;
    int d0 = lane * 8;
    float av[8], mv[8], gg[8], bb[8];
    load4(ar + d0, av); load4(ar + d0 + 4, av + 4);
    load4(mr + d0, mv); load4(mr + d0 + 4, mv + 4);
    load4(g + d0, gg);  load4(g + d0 + 4, gg + 4);
    load4(bt + d0, bb); load4(bt + d0 + 4, bb + 4);
    float v[8];
    float s = 0.f, s2 = 0.f;
    #pragma unroll
    for (int u = 0; u < 8; u++) { v[u] = av[u] + mv[u]; s += v[u]; s2 += v[u] * v[u]; }
    s = wave_sum(s); s2 = wave_sum(s2);
    float mu = s * (1.f / DD);
    float var = s2 * (1.f / DD) - mu * mu;
    float rs = rsqrtf(var + 1e-5f);
    #pragma unroll
    for (int u = 0; u < 8; u++) out[(size_t)r * DD + d0 + u] = f2b((v[u] - mu) * rs * gg[u] + bb[u]);
}

template <typename OT>
__global__ __launch_bounds__(256) void ln_rows_kernel(const u16* __restrict__ a,
                                                      const u16* __restrict__ bsrc,
                                                      const float* __restrict__ g,
                                                      const float* __restrict__ bt,
                                                      OT* __restrict__ out) {
    int r = blockIdx.x * 4 + (threadIdx.x >> 6);
    int lane = threadIdx.x & 63;
    const u16* ar = a + (size_t)r * DD;
    const u16* br = bsrc + (size_t)r * DD;
    int d0 = lane * 8;
    float av[8], cv[8], gg[8], bb[8];
    load4(ar + d0, av); load4(ar + d0 + 4, av + 4);
    load4(br + d0, cv); load4(br + d0 + 4, cv + 4);
    load4(g + d0, gg);  load4(g + d0 + 4, gg + 4);
    load4(bt + d0, bb); load4(bt + d0 + 4, bb + 4);
    float v[8];
    float s = 0.f, s2 = 0.f;
    #pragma unroll
    for (int u = 0; u < 8; u++) { v[u] = av[u] + cv[u]; s += v[u]; s2 += v[u] * v[u]; }
    s = wave_sum(s); s2 = wave_sum(s2);
    float mu = s * (1.f / DD);
    float var = s2 * (1.f / DD) - mu * mu;
    float rs = rsqrtf(var + 1e-5f);
    #pragma unroll
    for (int u = 0; u < 8; u++) st1(out + (size_t)r * DD + d0 + u, (v[u] - mu) * rs * gg[u] + bb[u]);
}

// ---------------- MFMA GEMM, double-buffered global_load_lds (R8-exact) ----------------
// C = act(A[M,K] @ W[N,K]^T + bias). BM = MT*32, BN=128, BK=32, 4 waves (2x2).
// Per K-step: issue next tile's DMA into buf^1, compute buf, ONE __syncthreads.
// KV=1: store C head-major kvb[part][b][h][s][64] (part=col>>9, h=(col>>6)&7).
template <int RELU, int MT, int KV>
__global__ __launch_bounds__(256) void gemm_lds(const u16* __restrict__ A,
                                                const u16* __restrict__ W,
                                                const float* __restrict__ bias,
                                                u16* __restrict__ C,
                                                int M, int N, int K) {
    constexpr int BM = MT * 32;
    constexpr int NIA = BM / 64;   // A DMA insts per wave
    __shared__ u16 As[2][BM * 32];
    __shared__ u16 Bs[2][128 * 32];
    int tid = threadIdx.x;
    int w = tid >> 6, lane = tid & 63;
    int n16 = lane & 15, quad = lane >> 4;
    int m0 = blockIdx.y * BM, n0 = blockIdx.x * 128;
    int wm16 = (w >> 1) * MT;       // m-block base (16-row units) for frags
    int wn = (w & 1) * 64;

    const u16* gA[NIA];
    u16* lA[NIA];
    #pragma unroll
    for (int i = 0; i < NIA; i++) {
        int s = (w * NIA + i) * 64 + lane;
        int mb = s >> 6, kseg = (s >> 4) & 3, m = s & 15;
        gA[i] = A + (size_t)(m0 + mb * 16 + m) * K + kseg * 8;
        lA[i] = &As[0][(size_t)((w * NIA + i) * 64) * 8];
    }
    const u16* gB[2];
    u16* lB[2];
    #pragma unroll
    for (int i = 0; i < 2; i++) {
        int s = (w * 2 + i) * 64 + lane;
        int nb = s >> 6, kseg = (s >> 4) & 3, n = s & 15;
        gB[i] = W + (size_t)(n0 + nb * 16 + n) * K + kseg * 8;
        lB[i] = &Bs[0][(size_t)((w * 2 + i) * 64) * 8];
    }

    f32x4 acc[MT][4];
    #pragma unroll
    for (int i = 0; i < MT; i++)
        #pragma unroll
        for (int j = 0; j < 4; j++) acc[i][j] = (f32x4){0.f, 0.f, 0.f, 0.f};

    const int nk = K >> 5;
    // prologue: stage tile 0 into buffer 0
    #pragma unroll
    for (int i = 0; i < NIA; i++) async16(gA[i], lA[i]);
    #pragma unroll
    for (int i = 0; i < 2; i++) async16(gB[i], lB[i]);
    __syncthreads();

    for (int t = 0; t < nk; t++) {
        int cur = t & 1;
        if (t + 1 < nk) {
            int nxt = cur ^ 1;
            #pragma unroll
            for (int i = 0; i < NIA; i++) async16(gA[i] + (t + 1) * 32, lA[i] + nxt * (BM * 32));
            #pragma unroll
            for (int i = 0; i < 2; i++) async16(gB[i] + (t + 1) * 32, lB[i] + nxt * 4096);
        }
        const u16* Ac = &As[cur][0];
        const u16* Bc = &Bs[cur][0];
        short8_t af[MT], bf[4];
        #pragma unroll
        for (int im = 0; im < MT; im++)
            af[im] = *(const short8_t*)(Ac + (size_t)((wm16 + im) * 64 + lane) * 8);
        #pragma unroll
        for (int in = 0; in < 4; in++)
            bf[in] = *(const short8_t*)(Bc + (size_t)(((w & 1) * 4 + in) * 64 + lane) * 8);
        #pragma unroll
        for (int im = 0; im < MT; im++)
            #pragma unroll
            for (int in = 0; in < 4; in++)
                acc[im][in] = __builtin_amdgcn_mfma_f32_16x16x32_bf16(af[im], bf[in], acc[im][in], 0, 0, 0);
        __syncthreads();   // drains next-tile DMA; all waves done reading cur
    }

    float bia[4];
    #pragma unroll
    for (int in = 0; in < 4; in++) bia[in] = bias[n0 + wn + in * 16 + n16];
    #pragma unroll
    for (int im = 0; im < MT; im++) {
        #pragma unroll
        for (int r = 0; r < 4; r++) {
            int row = m0 + (wm16 + im) * 16 + quad * 4 + r;
            #pragma unroll
            for (int in = 0; in < 4; in++) {
                float v = acc[im][in][r] + bia[in];
                if (RELU) v = fmaxf(v, 0.f);
                if (KV) {
                    int col = n0 + wn + in * 16 + n16;
                    int part = col >> 9, h = (col >> 6) & 7, d = col & 63;
                    int s = row >> 3, bq = row & 7;
                    C[(size_t)part * KVPART + ((size_t)(bq * HH + h) * SS + s) * DH + d] = f2b(v);
                } else {
                    C[(size_t)row * N + n0 + wn + in * 16 + n16] = f2b(v);
                }
            }
        }
    }
}

// ---------------- MFMA flash attention, swapped-QK in-register P ----------------
// grid (T/128, B*H), 4 waves; wave w owns 32 q-rows (2 q-tiles). XCD swizzle
// keeps each (b,h)'s 256KB KV slice on one XCD (FETCH 12MB, R9-proven).
// QK^T computed SWAPPED: sc = mfma(K, Q) -> lane holds S[key=quad*4+r][q=n16].
// Under key-permutation sigma (pos quad*8+j <-> key nt-interleaved), each lane
// then holds exactly its PV A-fragment: ap = cvt_pk(p0..p7) — P never touches
// LDS. V is staged in sigma order (per-lane key0 remap; still two adjacent
// 8B rows per lane, 2-way-free bank writes). K: global_load_lds frag-order.
// 1-deep prefetch; per-chunk __syncthreads. Fixed softmax max M=8.
__global__ __launch_bounds__(256) void attn_wp(const u16* __restrict__ qb,
                                               const u16* __restrict__ kvb,
                                               u16* __restrict__ ob) {
    __shared__ u16 Kb[2][2048];        // fragment order, 4KB per buffer
    __shared__ u16 Vt[2][64][40];      // V^T [d][pos], stride 40 (2-way free)
    int tid = threadIdx.x;
    int w = tid >> 6, lane = tid & 63;
    int n16 = lane & 15, quad = lane >> 4, q8 = quad * 8;
    int xb, bh;
    xcd_remap(xb, bh);
    int b = bh >> 3, h = bh & 7;
    int q0 = xb * 128 + w * 32;

    short8_t aq[2][2];
    #pragma unroll
    for (int qt = 0; qt < 2; qt++) {
        const u16* qrow = qb + ((size_t)(q0 + qt * 16 + n16) * BB + b) * DD + h * DH;
        aq[qt][0] = *(const short8_t*)(qrow + q8);
        aq[qt][1] = *(const short8_t*)(qrow + 32 + q8);
    }

    const u16* kbase = kvb + (size_t)(b * HH + h) * (SS * DH);
    const u16* vbase = kvb + (size_t)KVPART + (size_t)(b * HH + h) * (SS * DH);

    // K DMA: wave w stages frag f=w (nt = w>>1, kh = w&1).
    const u16* gK = kbase + (size_t)((w >> 1) * 16 + n16) * DH + (w & 1) * 32 + q8;

    // V staging under sigma: lane owns positions {2m, 2m+1} (m = lane&15),
    // holding keys {key0, key0+1}: key0 = b2<2 ? 4a+2b2 : 16+4a+2(b2-2).
    int m = lane & 15;
    int a2 = m >> 2, b2 = m & 3;
    int key0 = (b2 < 2) ? (4 * a2 + 2 * b2) : (16 + 4 * a2 + 2 * (b2 - 2));
    int kp2 = m * 2;
    int vd = w * 16 + quad * 4;
    const u16* gV = vbase + (size_t)key0 * DH + vd;

    float lsum[2] = {0.f, 0.f};
    f32x4 Oa[2][4];
    #pragma unroll
    for (int qt = 0; qt < 2; qt++)
        #pragma unroll
        for (int ot = 0; ot < 4; ot++) Oa[qt][ot] = (f32x4){0.f, 0.f, 0.f, 0.f};

    union VU { ushort4 q; u16 h[4]; };
    union PU { u32 wd[4]; short8_t s8; };

    // ---- stage chunk 0 ----
    {
        async16(gK, &Kb[0][w * 512]);
        VU va, vb2;
        va.q  = *(const ushort4*)(gV);
        vb2.q = *(const ushort4*)(gV + DH);
        #pragma unroll
        for (int u = 0; u < 4; u++)
            *(u32*)&Vt[0][vd + u][kp2] = (u32)va.h[u] | ((u32)vb2.h[u] << 16);
    }
    __syncthreads();

    for (int c = 0; c < 16; c++) {
        int cur = c & 1, nxt = cur ^ 1;

        // ---- prefetch chunk c+1 (issue loads; consume after compute) ----
        VU va, vb2;
        if (c < 15) {
            const u16* gVc = gV + (size_t)(c + 1) * 32 * DH;
            va.q  = *(const ushort4*)(gVc);
            vb2.q = *(const ushort4*)(gVc + DH);
            async16(gK + (size_t)(c + 1) * 32 * DH, &Kb[nxt][w * 512]);
        }

        short8_t bk0 = *(const short8_t*)&Kb[cur][0 * 512 + lane * 8];
        short8_t bk1 = *(const short8_t*)&Kb[cur][1 * 512 + lane * 8];
        short8_t bk2 = *(const short8_t*)&Kb[cur][2 * 512 + lane * 8];
        short8_t bk3 = *(const short8_t*)&Kb[cur][3 * 512 + lane * 8];

        #pragma unroll
        for (int qt = 0; qt < 2; qt++) {
            // swapped QK^T: sc[nt] = K_nt * Q  -> D[key=quad*4+r][q=n16]
            f32x4 s0 = (f32x4){0.f, 0.f, 0.f, 0.f};
            s0 = __builtin_amdgcn_mfma_f32_16x16x32_bf16(bk0, aq[qt][0], s0, 0, 0, 0);
            s0 = __builtin_amdgcn_mfma_f32_16x16x32_bf16(bk1, aq[qt][1], s0, 0, 0, 0);
            f32x4 s1 = (f32x4){0.f, 0.f, 0.f, 0.f};
            s1 = __builtin_amdgcn_mfma_f32_16x16x32_bf16(bk2, aq[qt][0], s1, 0, 0, 0);
            s1 = __builtin_amdgcn_mfma_f32_16x16x32_bf16(bk3, aq[qt][1], s1, 0, 0, 0);

            // fixed-max softmax, all in registers
            float p0 = __expf(s0[0] * 0.125f - 8.0f);
            float p1 = __expf(s0[1] * 0.125f - 8.0f);
            float p2 = __expf(s0[2] * 0.125f - 8.0f);
            float p3 = __expf(s0[3] * 0.125f - 8.0f);
            float p4 = __expf(s1[0] * 0.125f - 8.0f);
            float p5 = __expf(s1[1] * 0.125f - 8.0f);
            float p6 = __expf(s1[2] * 0.125f - 8.0f);
            float p7 = __expf(s1[3] * 0.125f - 8.0f);
            lsum[qt] += ((p0 + p1) + (p2 + p3)) + ((p4 + p5) + (p6 + p7));

            PU pu;
            pu.wd[0] = cvt_pk_bf16(p0, p1);
            pu.wd[1] = cvt_pk_bf16(p2, p3);
            pu.wd[2] = cvt_pk_bf16(p4, p5);
            pu.wd[3] = cvt_pk_bf16(p6, p7);

            // O += P @ V (A = P in-register, B = V from sigma-ordered Vt)
            #pragma unroll
            for (int ot = 0; ot < 4; ot++) {
                short8_t bv = *(const short8_t*)&Vt[cur][ot * 16 + n16][q8];
                Oa[qt][ot] = __builtin_amdgcn_mfma_f32_16x16x32_bf16(pu.s8, bv, Oa[qt][ot], 0, 0, 0);
            }
        }

        // ---- write prefetched V into Vt[nxt] ----
        if (c < 15) {
            #pragma unroll
            for (int u = 0; u < 4; u++)
                *(u32*)&Vt[nxt][vd + u][kp2] = (u32)va.h[u] | ((u32)vb2.h[u] << 16);
        }
        __syncthreads();   // drains my K-DMA (vmcnt0) + orders LDS across waves
    }

    #pragma unroll
    for (int qt = 0; qt < 2; qt++) {
        // lsum[qt] is partial for q=n16 over this quad's 8 keys; sum quads
        float l = lsum[qt];
        l += __shfl_xor(l, 16, 64);
        l += __shfl_xor(l, 32, 64);
        #pragma unroll
        for (int r = 0; r < 4; r++) {
            float lq = __shfl(l, quad * 4 + r, 64);   // l for q = quad*4+r
            float inv = 1.f / lq;
            int t = q0 + qt * 16 + quad * 4 + r;
            u16* orow = ob + ((size_t)t * BB + b) * DD + h * DH + n16;
            #pragma unroll
            for (int ot = 0; ot < 4; ot++) orow[ot * 16] = f2b(Oa[qt][ot][r] * inv);
        }
    }
}

// ---------------- host ----------------
extern "C" void kernel_launch(void* const* d_in, const int* in_sizes, int n_in,
                              void* d_out, int out_size, void* d_ws, size_t ws_size,
                              hipStream_t stream) {
    const float* tgt       = (const float*)d_in[0];
    const float* memory    = (const float*)d_in[1];
    const float* queries   = (const float*)d_in[2];
    const float* wk        = (const float*)d_in[3];
    const float* in_proj_w = (const float*)d_in[4];
    const float* in_proj_b = (const float*)d_in[5];
    const float* out_proj_w= (const float*)d_in[6];
    const float* out_proj_b= (const float*)d_in[7];
    const float* lin1_w    = (const float*)d_in[8];
    const float* lin1_b    = (const float*)d_in[9];
    const float* lin2_w    = (const float*)d_in[10];
    const float* lin2_b    = (const float*)d_in[11];
    const float* ln1_g     = (const float*)d_in[12];
    const float* ln1_b     = (const float*)d_in[13];
    const float* ln2_g     = (const float*)d_in[14];
    const float* ln2_b     = (const float*)d_in[15];
    const float* ln3_g     = (const float*)d_in[16];
    const float* ln3_b     = (const float*)d_in[17];

    char* w = (char*)d_ws;
    float* qeff  = (float*)(w + 0);
    float* pbuf  = (float*)(w + 20480);
    float* mixed = (float*)(w + 872448);
    u16* y1  = (u16*)(w + 2969600);
    u16* qb  = (u16*)(w + 19746816);
    u16* kvb = (u16*)(w + 36524032);   // 8.4MB head-major KV
    u16* ob  = (u16*)(w + 44912640);
    // pre-attention residents of the ob region (dead before attn writes ob):
    u16* ipwb = (u16*)(w + 44912640);  // in_proj_w bf16 [1536*512]
    u16* memb = (u16*)(w + 46485504);  // memory bf16 [4096*512]
    // post-attention residents of the kvb region (kvb dead after attn):
    u16* opwb = (u16*)(w + 36524032);  // out_proj_w bf16 [512*512]
    u16* l1wb = (u16*)(w + 37048320);  // lin1_w bf16 [2048*512]
    u16* l2wb = (u16*)(w + 39145472);  // lin2_w bf16 [512*2048]
    u16* t1 = qb;  // out_proj result (qb dead after attention)
    u16* y2 = ob;  // LN2 out (ob = attn out, dead after out_proj)
    u16* hb = qb;  // FFN hidden chunk 4096x2048 (qb/t1 dead after LN2)
    u16* fb = y1;  // lin2 out (y1 dead after LN2)

    // ---- pre-attention conversions (memory + in_proj_w, fused) ----
    cvt2_kernel<<<2816, 256, 0, stream>>>(memory, in_proj_w, memb, ipwb);

    // ---- QA block ----
    qeff_kernel<<<1, 512, 0, stream>>>(queries, qeff);
    p_kernel<<<BB * (TT / 4), 256, 0, stream>>>(tgt, qeff, pbuf);
    winmix_kernel<<<BB * NW, 256, 0, stream>>>(pbuf, wk, tgt, mixed);
    ln_qa_kernel<<<(TT * BB) / 4, 256, 0, stream>>>(tgt, mixed, ln1_g, ln1_b, y1);

    // ---- MHA ----
    gemm_lds<0, 4, 0><<<dim3(DD / 128, (TT * BB) / 128), 256, 0, stream>>>(y1, ipwb, in_proj_b, qb, TT * BB, DD, DD);
    gemm_lds<0, 4, 1><<<dim3(1024 / 128, (SS * BB) / 128), 256, 0, stream>>>(memb, ipwb + (size_t)DD * DD, in_proj_b + DD, kvb, SS * BB, 1024, DD);
    attn_wp<<<dim3(TT / 128, BB * HH), 256, 0, stream>>>(qb, kvb, ob);
    // kvb dead; convert remaining weights into its region (fused)
    cvt3_kernel<<<2304, 256, 0, stream>>>(out_proj_w, lin1_w, lin2_w, opwb, l1wb, l2wb);
    gemm_lds<0, 4, 0><<<dim3(DD / 128, (TT * BB) / 128), 256, 0, stream>>>(ob, opwb, out_proj_b, t1, TT * BB, DD, DD);
    ln_rows_kernel<u16><<<(TT * BB) / 4, 256, 0, stream>>>(y1, t1, ln2_g, ln2_b, y2);

    // ---- FFN (4 chunks of 4096 rows; hidden in qb region) ----
    for (int c = 0; c < 4; c++) {
        const u16* y2c = y2 + (size_t)c * 4096 * DD;
        u16* fbc = fb + (size_t)c * 4096 * DD;
        gemm_lds<1, 4, 0><<<dim3(DFF / 128, 4096 / 128), 256, 0, stream>>>(y2c, l1wb, lin1_b, hb, 4096, DFF, DD);
        gemm_lds<0, 2, 0><<<dim3(DD / 128, 4096 / 64), 256, 0, stream>>>(hb, l2wb, lin2_b, fbc, 4096, DD, DFF);
    }
    ln_rows_kernel<float><<<(TT * BB) / 4, 256, 0, stream>>>(y2, fb, ln3_g, ln3_b, (float*)d_out);
}

// Round 6
// 533.529 us; speedup vs baseline: 1.1272x; 1.0095x over previous
//
#include <hip/hip_runtime.h>

// TransformerDecoderLayerQaN — MI355X round 12.
// R12 = R11 + gemm_np: narrow-N GEMM (BM=64, BN=64, 2m x 2n waves, 3 LDS
// buffers, 2-deep prefetch with counted s_waitcnt vmcnt(2) + raw s_barrier)
// for the two 1-block/CU dispatches diagnosed in R11: lin2 (41.8us x4,
// Occupancy 9.6%, latency-bound) and the KV projection (256 blocks).
// Grid: lin2 256->512 blocks (2/CU), kv 256->1024 (4/CU). Everything else
// (R8-exact gemm_lds, R11 attn, fused cvt/winmix) unchanged.
//
// ws layout (total 61,689,856 B — same envelope):
//   qeff  f32 [10*512]   @ 0
//   p     f32 [B*NQ*T]   @ 20480
//   mixed f32 [B*NW*D]   @ 872448
//   y1    bf16 [T*B*D]   @ 2969600    (reused: fb = lin2 out)
//   qb    bf16 [T*B*D]   @ 19746816   (reused: t1 = out_proj out; hb = FFN hidden)
//   kvb   bf16 [2][B][H][S][64] @ 36524032  (K part 0, V part 1; 8.4MB)
//     post-attn reuse: opwb @36524032, l1wb @37048320, l2wb @39145472
//   ob    bf16 [T*B*D]   @ 44912640   (reused: y2 = LN2 out)
//     pre-attn reuse: ipwb bf16[1536*512] @44912640, memb bf16[4096*512] @46485504

typedef unsigned short u16;
typedef unsigned int u32;
typedef short short8_t __attribute__((ext_vector_type(8)));
typedef float f32x4 __attribute__((ext_vector_type(4)));

#define TT 2048
#define BB 8
#define SS 512
#define DD 512
#define HH 8
#define DH 64
#define DFF 2048
#define NQ 10
#define WW 16
#define NW 128
#define KVPART 2097152   // elems per K / V part: B*H*S*DH = 8*8*512*64

__device__ __forceinline__ float b2f(u16 u) {
    return __uint_as_float(((unsigned int)u) << 16);
}
__device__ __forceinline__ u16 f2b(float f) {
    unsigned int x = __float_as_uint(f);
    unsigned int r = x + 0x7FFFu + ((x >> 16) & 1u);
    return (u16)(r >> 16);
}
__device__ __forceinline__ u32 cvt_pk_bf16(float lo, float hi) {
    u32 r;
    asm volatile("v_cvt_pk_bf16_f32 %0, %1, %2" : "=v"(r) : "v"(lo), "v"(hi));
    return r;
}
__device__ __forceinline__ float wave_sum(float v) {
    #pragma unroll
    for (int o = 32; o > 0; o >>= 1) v += __shfl_xor(v, o, 64);
    return v;
}
__device__ __forceinline__ float wave_max(float v) {
    #pragma unroll
    for (int o = 32; o > 0; o >>= 1) v = fmaxf(v, __shfl_xor(v, o, 64));
    return v;
}
__device__ __forceinline__ void load4(const u16* p, float* v) {
    ushort4 t = *(const ushort4*)p;
    v[0] = b2f(t.x); v[1] = b2f(t.y); v[2] = b2f(t.z); v[3] = b2f(t.w);
}
__device__ __forceinline__ void load4(const float* p, float* v) {
    float4 t = *(const float4*)p;
    v[0] = t.x; v[1] = t.y; v[2] = t.z; v[3] = t.w;
}
__device__ __forceinline__ void st1(u16* p, float v) { *p = f2b(v); }
__device__ __forceinline__ void st1(float* p, float v) { *p = v; }

// async global->LDS, 16B per lane; lds dest = wave-uniform base + lane*16
__device__ __forceinline__ void async16(const u16* g, u16* l) {
    __builtin_amdgcn_global_load_lds((const __attribute__((address_space(1))) u32*)g,
                                     (__attribute__((address_space(3))) u32*)l, 16, 0, 0);
}

// reuse-grouped XCD swizzle (attn only): flat%8 = XCD; all gx blocks of a
// y-panel -> same XCD L2. Requires gy%8==0. Proven: attn FETCH 41->12MB (R9).
__device__ __forceinline__ void xcd_remap(int& bx, int& by) {
    int flat = blockIdx.y * gridDim.x + blockIdx.x;
    int xcd = flat & 7;
    int j = flat >> 3;
    by = xcd * ((int)gridDim.y >> 3) + j / (int)gridDim.x;
    bx = j % (int)gridDim.x;
}

// ---------------- fused f32 -> bf16 converts ----------------
__device__ __forceinline__ void cvt_block(const float* s, u16* d, int base) {
    int i = base + threadIdx.x * 4;
    float4 v = *(const float4*)(s + i);
    ushort4 o;
    o.x = f2b(v.x); o.y = f2b(v.y); o.z = f2b(v.z); o.w = f2b(v.w);
    *(ushort4*)(d + i) = o;
}

// memory (2,097,152 f32 -> 2048 blocks) + in_proj_w (786,432 -> 768 blocks)
__global__ __launch_bounds__(256) void cvt2_kernel(const float* __restrict__ s0,
                                                   const float* __restrict__ s1,
                                                   u16* __restrict__ d0,
                                                   u16* __restrict__ d1) {
    int bid = blockIdx.x;
    if (bid < 2048) cvt_block(s0, d0, bid * 1024);
    else            cvt_block(s1, d1, (bid - 2048) * 1024);
}

// out_proj_w (262,144 -> 256) + lin1_w (1,048,576 -> 1024) + lin2_w (1024)
__global__ __launch_bounds__(256) void cvt3_kernel(const float* __restrict__ s0,
                                                   const float* __restrict__ s1,
                                                   const float* __restrict__ s2,
                                                   u16* __restrict__ d0,
                                                   u16* __restrict__ d1,
                                                   u16* __restrict__ d2) {
    int bid = blockIdx.x;
    if (bid < 256)       cvt_block(s0, d0, bid * 1024);
    else if (bid < 1280) cvt_block(s1, d1, (bid - 256) * 1024);
    else                 cvt_block(s2, d2, (bid - 1280) * 1024);
}

// ---------------- QA block ----------------
__global__ __launch_bounds__(512) void qeff_kernel(const float* __restrict__ queries,
                                                   float* __restrict__ qeff) {
    int d = threadIdx.x;
    const float KS = 0.0055242717280199026f; // 1/(8*sqrt(512))
    for (int n = 0; n < NQ; n++) {
        float v = queries[n * DD + d];
        float ss = wave_sum(v * v);
        float norm = sqrtf(ss);
        qeff[n * DD + d] = v / (norm + 1e-6f) * KS;
    }
}

__global__ __launch_bounds__(256) void p_kernel(const float* __restrict__ x,
                                                const float* __restrict__ qeff,
                                                float* __restrict__ p) {
    __shared__ float qe[NQ * DD];
    for (int i = threadIdx.x; i < NQ * DD; i += 256) qe[i] = qeff[i];
    __syncthreads();
    int b = blockIdx.x >> 9;
    int t = ((blockIdx.x & 511) << 2) + (threadIdx.x >> 6);
    int lane = threadIdx.x & 63;
    const float* xr = x + ((size_t)t * BB + b) * DD;
    float acc[NQ];
    #pragma unroll
    for (int n = 0; n < NQ; n++) acc[n] = 0.f;
    #pragma unroll
    for (int c = 0; c < 8; c++) {
        int d = c * 64 + lane;
        float xv = xr[d];
        #pragma unroll
        for (int n = 0; n < NQ; n++) acc[n] += xv * qe[n * DD + d];
    }
    #pragma unroll
    for (int n = 0; n < NQ; n++) {
        float s = wave_sum(acc[n]);
        if (lane == 0) p[((size_t)(b * NQ + n)) * TT + t] = s;
    }
}

// fused win + mix: wave 0 computes the 48 combined softmax weights, then all
// 256 threads do the weighted row mix.
__global__ __launch_bounds__(256) void winmix_kernel(const float* __restrict__ p,
                                                     const float* __restrict__ wk,
                                                     const float* __restrict__ x,
                                                     float* __restrict__ mixed) {
    __shared__ float As[48];
    int id = blockIdx.x;
    int b = id >> 7, m = id & 127;
    if (threadIdx.x < 64) {
        int j = threadIdx.x;
        int tj = (m - 1) * WW + j;
        bool valid = (j < 48) && (tj >= 0) && (tj < TT);
        float acc = 0.f;
        for (int n = 0; n < NQ; n++) {
            float v = valid ? p[((size_t)(b * NQ + n)) * TT + tj] : -1e30f;
            float mx = wave_max(v);
            float e = valid ? __expf(v - mx) : 0.f;
            float s = wave_sum(e);
            acc += wk[n] * (e / s);
        }
        if (j < 48) As[j] = acc;
    }
    __syncthreads();
    int d0 = threadIdx.x, d1 = threadIdx.x + 256;
    float a0 = 0.f, a1 = 0.f;
    int tb = (m - 1) * WW;
    for (int j = 0; j < 48; j++) {
        int t = tb + j;
        if ((unsigned)t < (unsigned)TT) {
            float aj = As[j];
            const float* xr = x + ((size_t)t * BB + b) * DD;
            a0 += aj * xr[d0];
            a1 += aj * xr[d1];
        }
    }
    mixed[(size_t)id * DD + d0] = a0;
    mixed[(size_t)id * DD + d1] = a1;
}

__global__ __launch_bounds__(256) void ln_qa_kernel(const float* __restrict__ a,
                                                    const float* __restrict__ mixed,
                                                    const float* __restrict__ g,
                                                    const float* __restrict__ bt,
                                                    u16* __restrict__ out) {
    int r = blockIdx.x * 4 + (threadIdx.x >> 6); // r = t*B+b
    int lane = threadIdx.x & 63;
    int t = r >> 3, b = r & 7;
    const float* ar = a + (size_t)r * DD;
    const float* mr = mixed + ((size_t)(b * NW + (t >> 4))) * DD;
    int d0 = lane * 8;
    float av[8], mv[8], gg[8], bb[8];
    load4(ar + d0, av); load4(ar + d0 + 4, av + 4);
    load4(mr + d0, mv); load4(mr + d0 + 4, mv + 4);
    load4(g + d0, gg);  load4(g + d0 + 4, gg + 4);
    load4(bt + d0, bb); load4(bt + d0 + 4, bb + 4);
    float v[8];
    float s = 0.f, s2 = 0.f;
    #pragma unroll
    for (int u = 0; u < 8; u++) { v[u] = av[u] + mv[u]; s += v[u]; s2 += v[u] * v[u]; }
    s = wave_sum(s); s2 = wave_sum(s2);
    float mu = s * (1.f / DD);
    float var = s2 * (1.f / DD) - mu * mu;
    float rs = rsqrtf(var + 1e-5f);
    #pragma unroll
    for (int u = 0; u < 8; u++) out[(size_t)r * DD + d0 + u] = f2b((v[u] - mu) * rs * gg[u] + bb[u]);
}

template <typename OT>
__global__ __launch_bounds__(256) void ln_rows_kernel(const u16* __restrict__ a,
                                                      const u16* __restrict__ bsrc,
                                                      const float* __restrict__ g,
                                                      const float* __restrict__ bt,
                                                      OT* __restrict__ out) {
    int r = blockIdx.x * 4 + (threadIdx.x >> 6);
    int lane = threadIdx.x & 63;
    const u16* ar = a + (size_t)r * DD;
    const u16* br = bsrc + (size_t)r * DD;
    int d0 = lane * 8;
    float av[8], cv[8], gg[8], bb[8];
    load4(ar + d0, av); load4(ar + d0 + 4, av + 4);
    load4(br + d0, cv); load4(br + d0 + 4, cv + 4);
    load4(g + d0, gg);  load4(g + d0 + 4, gg + 4);
    load4(bt + d0, bb); load4(bt + d0 + 4, bb + 4);
    float v[8];
    float s = 0.f, s2 = 0.f;
    #pragma unroll
    for (int u = 0; u < 8; u++) { v[u] = av[u] + cv[u]; s += v[u]; s2 += v[u] * v[u]; }
    s = wave_sum(s); s2 = wave_sum(s2);
    float mu = s * (1.f / DD);
    float var = s2 * (1.f / DD) - mu * mu;
    float rs = rsqrtf(var + 1e-5f);
    #pragma unroll
    for (int u = 0; u < 8; u++) st1(out + (size_t)r * DD + d0 + u, (v[u] - mu) * rs * gg[u] + bb[u]);
}

// ---------------- MFMA GEMM, double-buffered global_load_lds (R8-exact) ----------------
// C = act(A[M,K] @ W[N,K]^T + bias). BM = MT*32, BN=128, BK=32, 4 waves (2x2).
template <int RELU, int MT, int KV>
__global__ __launch_bounds__(256) void gemm_lds(const u16* __restrict__ A,
                                                const u16* __restrict__ W,
                                                const float* __restrict__ bias,
                                                u16* __restrict__ C,
                                                int M, int N, int K) {
    constexpr int BM = MT * 32;
    constexpr int NIA = BM / 64;   // A DMA insts per wave
    __shared__ u16 As[2][BM * 32];
    __shared__ u16 Bs[2][128 * 32];
    int tid = threadIdx.x;
    int w = tid >> 6, lane = tid & 63;
    int n16 = lane & 15, quad = lane >> 4;
    int m0 = blockIdx.y * BM, n0 = blockIdx.x * 128;
    int wm16 = (w >> 1) * MT;       // m-block base (16-row units) for frags
    int wn = (w & 1) * 64;

    const u16* gA[NIA];
    u16* lA[NIA];
    #pragma unroll
    for (int i = 0; i < NIA; i++) {
        int s = (w * NIA + i) * 64 + lane;
        int mb = s >> 6, kseg = (s >> 4) & 3, m = s & 15;
        gA[i] = A + (size_t)(m0 + mb * 16 + m) * K + kseg * 8;
        lA[i] = &As[0][(size_t)((w * NIA + i) * 64) * 8];
    }
    const u16* gB[2];
    u16* lB[2];
    #pragma unroll
    for (int i = 0; i < 2; i++) {
        int s = (w * 2 + i) * 64 + lane;
        int nb = s >> 6, kseg = (s >> 4) & 3, n = s & 15;
        gB[i] = W + (size_t)(n0 + nb * 16 + n) * K + kseg * 8;
        lB[i] = &Bs[0][(size_t)((w * 2 + i) * 64) * 8];
    }

    f32x4 acc[MT][4];
    #pragma unroll
    for (int i = 0; i < MT; i++)
        #pragma unroll
        for (int j = 0; j < 4; j++) acc[i][j] = (f32x4){0.f, 0.f, 0.f, 0.f};

    const int nk = K >> 5;
    // prologue: stage tile 0 into buffer 0
    #pragma unroll
    for (int i = 0; i < NIA; i++) async16(gA[i], lA[i]);
    #pragma unroll
    for (int i = 0; i < 2; i++) async16(gB[i], lB[i]);
    __syncthreads();

    for (int t = 0; t < nk; t++) {
        int cur = t & 1;
        if (t + 1 < nk) {
            int nxt = cur ^ 1;
            #pragma unroll
            for (int i = 0; i < NIA; i++) async16(gA[i] + (t + 1) * 32, lA[i] + nxt * (BM * 32));
            #pragma unroll
            for (int i = 0; i < 2; i++) async16(gB[i] + (t + 1) * 32, lB[i] + nxt * 4096);
        }
        const u16* Ac = &As[cur][0];
        const u16* Bc = &Bs[cur][0];
        short8_t af[MT], bf[4];
        #pragma unroll
        for (int im = 0; im < MT; im++)
            af[im] = *(const short8_t*)(Ac + (size_t)((wm16 + im) * 64 + lane) * 8);
        #pragma unroll
        for (int in = 0; in < 4; in++)
            bf[in] = *(const short8_t*)(Bc + (size_t)(((w & 1) * 4 + in) * 64 + lane) * 8);
        #pragma unroll
        for (int im = 0; im < MT; im++)
            #pragma unroll
            for (int in = 0; in < 4; in++)
                acc[im][in] = __builtin_amdgcn_mfma_f32_16x16x32_bf16(af[im], bf[in], acc[im][in], 0, 0, 0);
        __syncthreads();   // drains next-tile DMA; all waves done reading cur
    }

    float bia[4];
    #pragma unroll
    for (int in = 0; in < 4; in++) bia[in] = bias[n0 + wn + in * 16 + n16];
    #pragma unroll
    for (int im = 0; im < MT; im++) {
        #pragma unroll
        for (int r = 0; r < 4; r++) {
            int row = m0 + (wm16 + im) * 16 + quad * 4 + r;
            #pragma unroll
            for (int in = 0; in < 4; in++) {
                float v = acc[im][in][r] + bia[in];
                if (RELU) v = fmaxf(v, 0.f);
                if (KV) {
                    int col = n0 + wn + in * 16 + n16;
                    int part = col >> 9, h = (col >> 6) & 7, d = col & 63;
                    int s = row >> 3, bq = row & 7;
                    C[(size_t)part * KVPART + ((size_t)(bq * HH + h) * SS + s) * DH + d] = f2b(v);
                } else {
                    C[(size_t)row * N + n0 + wn + in * 16 + n16] = f2b(v);
                }
            }
        }
    }
}

// ---------------- narrow-N MFMA GEMM, 2-deep pipelined (for 1-block/CU cases) ----------------
// BM=64, BN=64, BK=32; 4 waves as 2m x 2n (each wave 2x2 frags). 3 LDS
// buffers; iter t: [s_waitcnt vmcnt(2) -> s_barrier -> sched_barrier] ->
// issue stage(t+2) -> compute buf[t%3] -> lgkmcnt(0). Counted vmcnt keeps
// the 2 next-tile DMAs in flight across the barrier (never drains to 0).
// Per wave per stage: 1 A DMA + 1 B DMA (wave w stages m-unit w / n-unit w).
template <int RELU, int KV>
__global__ __launch_bounds__(256) void gemm_np(const u16* __restrict__ A,
                                               const u16* __restrict__ W,
                                               const float* __restrict__ bias,
                                               u16* __restrict__ C,
                                               int M, int N, int K) {
    __shared__ u16 As[3][64 * 32];
    __shared__ u16 Bs[3][64 * 32];
    int tid = threadIdx.x;
    int w = tid >> 6, lane = tid & 63;
    int n16 = lane & 15, quad = lane >> 4;
    int m0 = blockIdx.y * 64, n0 = blockIdx.x * 64;
    int wm16 = (w >> 1) * 2;        // m-unit base for frags
    int wn = (w & 1) * 32;

    const u16* gA0 = A + (size_t)(m0 + w * 16 + n16) * K + quad * 8;
    const u16* gB0 = W + (size_t)(n0 + w * 16 + n16) * K + quad * 8;

    f32x4 acc[2][2];
    #pragma unroll
    for (int i = 0; i < 2; i++)
        #pragma unroll
        for (int j = 0; j < 2; j++) acc[i][j] = (f32x4){0.f, 0.f, 0.f, 0.f};

    const int nk = K >> 5;
    // prologue: stage tiles 0 and 1
    async16(gA0, &As[0][w * 512]);
    async16(gB0, &Bs[0][w * 512]);
    async16(gA0 + 32, &As[1][w * 512]);
    async16(gB0 + 32, &Bs[1][w * 512]);

    int cur = 0;
    for (int t = 0; t < nk; t++) {
        if (t + 1 < nk) {
            __asm__ volatile("s_waitcnt vmcnt(2)" ::: "memory");
        } else {
            __asm__ volatile("s_waitcnt vmcnt(0)" ::: "memory");
        }
        __builtin_amdgcn_s_barrier();
        __builtin_amdgcn_sched_barrier(0);
        if (t + 2 < nk) {
            int nx2 = cur + 2; if (nx2 >= 3) nx2 -= 3;
            async16(gA0 + (t + 2) * 32, &As[nx2][w * 512]);
            async16(gB0 + (t + 2) * 32, &Bs[nx2][w * 512]);
        }
        const u16* Ac = &As[cur][0];
        const u16* Bc = &Bs[cur][0];
        short8_t af[2], bf[2];
        #pragma unroll
        for (int im = 0; im < 2; im++)
            af[im] = *(const short8_t*)(Ac + (size_t)((wm16 + im) * 64 + lane) * 8);
        #pragma unroll
        for (int in = 0; in < 2; in++)
            bf[in] = *(const short8_t*)(Bc + (size_t)(((w & 1) * 2 + in) * 64 + lane) * 8);
        #pragma unroll
        for (int im = 0; im < 2; im++)
            #pragma unroll
            for (int in = 0; in < 2; in++)
                acc[im][in] = __builtin_amdgcn_mfma_f32_16x16x32_bf16(af[im], bf[in], acc[im][in], 0, 0, 0);
        __asm__ volatile("s_waitcnt lgkmcnt(0)" ::: "memory");
        cur = (cur == 2) ? 0 : cur + 1;
    }

    float bia[2];
    #pragma unroll
    for (int in = 0; in < 2; in++) bia[in] = bias[n0 + wn + in * 16 + n16];
    #pragma unroll
    for (int im = 0; im < 2; im++) {
        #pragma unroll
        for (int r = 0; r < 4; r++) {
            int row = m0 + (wm16 + im) * 16 + quad * 4 + r;
            #pragma unroll
            for (int in = 0; in < 2; in++) {
                float v = acc[im][in][r] + bia[in];
                if (RELU) v = fmaxf(v, 0.f);
                if (KV) {
                    int col = n0 + wn + in * 16 + n16;
                    int part = col >> 9, h = (col >> 6) & 7, d = col & 63;
                    int s = row >> 3, bq = row & 7;
                    C[(size_t)part * KVPART + ((size_t)(bq * HH + h) * SS + s) * DH + d] = f2b(v);
                } else {
                    C[(size_t)row * N + n0 + wn + in * 16 + n16] = f2b(v);
                }
            }
        }
    }
}

// ---------------- MFMA flash attention, swapped-QK in-register P (R11) ----------------
__global__ __launch_bounds__(256) void attn_wp(const u16* __restrict__ qb,
                                               const u16* __restrict__ kvb,
                                               u16* __restrict__ ob) {
    __shared__ u16 Kb[2][2048];        // fragment order, 4KB per buffer
    __shared__ u16 Vt[2][64][40];      // V^T [d][pos], stride 40 (2-way free)
    int tid = threadIdx.x;
    int w = tid >> 6, lane = tid & 63;
    int n16 = lane & 15, quad = lane >> 4, q8 = quad * 8;
    int xb, bh;
    xcd_remap(xb, bh);
    int b = bh >> 3, h = bh & 7;
    int q0 = xb * 128 + w * 32;

    short8_t aq[2][2];
    #pragma unroll
    for (int qt = 0; qt < 2; qt++) {
        const u16* qrow = qb + ((size_t)(q0 + qt * 16 + n16) * BB + b) * DD + h * DH;
        aq[qt][0] = *(const short8_t*)(qrow + q8);
        aq[qt][1] = *(const short8_t*)(qrow + 32 + q8);
    }

    const u16* kbase = kvb + (size_t)(b * HH + h) * (SS * DH);
    const u16* vbase = kvb + (size_t)KVPART + (size_t)(b * HH + h) * (SS * DH);

    // K DMA: wave w stages frag f=w (nt = w>>1, kh = w&1).
    const u16* gK = kbase + (size_t)((w >> 1) * 16 + n16) * DH + (w & 1) * 32 + q8;

    // V staging under sigma: lane owns positions {2m, 2m+1} (m = lane&15),
    // holding keys {key0, key0+1}: key0 = b2<2 ? 4a+2b2 : 16+4a+2(b2-2).
    int m = lane & 15;
    int a2 = m >> 2, b2 = m & 3;
    int key0 = (b2 < 2) ? (4 * a2 + 2 * b2) : (16 + 4 * a2 + 2 * (b2 - 2));
    int kp2 = m * 2;
    int vd = w * 16 + quad * 4;
    const u16* gV = vbase + (size_t)key0 * DH + vd;

    float lsum[2] = {0.f, 0.f};
    f32x4 Oa[2][4];
    #pragma unroll
    for (int qt = 0; qt < 2; qt++)
        #pragma unroll
        for (int ot = 0; ot < 4; ot++) Oa[qt][ot] = (f32x4){0.f, 0.f, 0.f, 0.f};

    union VU { ushort4 q; u16 h[4]; };
    union PU { u32 wd[4]; short8_t s8; };

    // ---- stage chunk 0 ----
    {
        async16(gK, &Kb[0][w * 512]);
        VU va, vb2;
        va.q  = *(const ushort4*)(gV);
        vb2.q = *(const ushort4*)(gV + DH);
        #pragma unroll
        for (int u = 0; u < 4; u++)
            *(u32*)&Vt[0][vd + u][kp2] = (u32)va.h[u] | ((u32)vb2.h[u] << 16);
    }
    __syncthreads();

    for (int c = 0; c < 16; c++) {
        int cur = c & 1, nxt = cur ^ 1;

        // ---- prefetch chunk c+1 (issue loads; consume after compute) ----
        VU va, vb2;
        if (c < 15) {
            const u16* gVc = gV + (size_t)(c + 1) * 32 * DH;
            va.q  = *(const ushort4*)(gVc);
            vb2.q = *(const ushort4*)(gVc + DH);
            async16(gK + (size_t)(c + 1) * 32 * DH, &Kb[nxt][w * 512]);
        }

        short8_t bk0 = *(const short8_t*)&Kb[cur][0 * 512 + lane * 8];
        short8_t bk1 = *(const short8_t*)&Kb[cur][1 * 512 + lane * 8];
        short8_t bk2 = *(const short8_t*)&Kb[cur][2 * 512 + lane * 8];
        short8_t bk3 = *(const short8_t*)&Kb[cur][3 * 512 + lane * 8];

        #pragma unroll
        for (int qt = 0; qt < 2; qt++) {
            // swapped QK^T: sc[nt] = K_nt * Q  -> D[key=quad*4+r][q=n16]
            f32x4 s0 = (f32x4){0.f, 0.f, 0.f, 0.f};
            s0 = __builtin_amdgcn_mfma_f32_16x16x32_bf16(bk0, aq[qt][0], s0, 0, 0, 0);
            s0 = __builtin_amdgcn_mfma_f32_16x16x32_bf16(bk1, aq[qt][1], s0, 0, 0, 0);
            f32x4 s1 = (f32x4){0.f, 0.f, 0.f, 0.f};
            s1 = __builtin_amdgcn_mfma_f32_16x16x32_bf16(bk2, aq[qt][0], s1, 0, 0, 0);
            s1 = __builtin_amdgcn_mfma_f32_16x16x32_bf16(bk3, aq[qt][1], s1, 0, 0, 0);

            // fixed-max softmax, all in registers
            float p0 = __expf(s0[0] * 0.125f - 8.0f);
            float p1 = __expf(s0[1] * 0.125f - 8.0f);
            float p2 = __expf(s0[2] * 0.125f - 8.0f);
            float p3 = __expf(s0[3] * 0.125f - 8.0f);
            float p4 = __expf(s1[0] * 0.125f - 8.0f);
            float p5 = __expf(s1[1] * 0.125f - 8.0f);
            float p6 = __expf(s1[2] * 0.125f - 8.0f);
            float p7 = __expf(s1[3] * 0.125f - 8.0f);
            lsum[qt] += ((p0 + p1) + (p2 + p3)) + ((p4 + p5) + (p6 + p7));

            PU pu;
            pu.wd[0] = cvt_pk_bf16(p0, p1);
            pu.wd[1] = cvt_pk_bf16(p2, p3);
            pu.wd[2] = cvt_pk_bf16(p4, p5);
            pu.wd[3] = cvt_pk_bf16(p6, p7);

            // O += P @ V (A = P in-register, B = V from sigma-ordered Vt)
            #pragma unroll
            for (int ot = 0; ot < 4; ot++) {
                short8_t bv = *(const short8_t*)&Vt[cur][ot * 16 + n16][q8];
                Oa[qt][ot] = __builtin_amdgcn_mfma_f32_16x16x32_bf16(pu.s8, bv, Oa[qt][ot], 0, 0, 0);
            }
        }

        // ---- write prefetched V into Vt[nxt] ----
        if (c < 15) {
            #pragma unroll
            for (int u = 0; u < 4; u++)
                *(u32*)&Vt[nxt][vd + u][kp2] = (u32)va.h[u] | ((u32)vb2.h[u] << 16);
        }
        __syncthreads();   // drains my K-DMA (vmcnt0) + orders LDS across waves
    }

    #pragma unroll
    for (int qt = 0; qt < 2; qt++) {
        // lsum[qt] is partial for q=n16 over this quad's 8 keys; sum quads
        float l = lsum[qt];
        l += __shfl_xor(l, 16, 64);
        l += __shfl_xor(l, 32, 64);
        #pragma unroll
        for (int r = 0; r < 4; r++) {
            float lq = __shfl(l, quad * 4 + r, 64);   // l for q = quad*4+r
            float inv = 1.f / lq;
            int t = q0 + qt * 16 + quad * 4 + r;
            u16* orow = ob + ((size_t)t * BB + b) * DD + h * DH + n16;
            #pragma unroll
            for (int ot = 0; ot < 4; ot++) orow[ot * 16] = f2b(Oa[qt][ot][r] * inv);
        }
    }
}

// ---------------- host ----------------
extern "C" void kernel_launch(void* const* d_in, const int* in_sizes, int n_in,
                              void* d_out, int out_size, void* d_ws, size_t ws_size,
                              hipStream_t stream) {
    const float* tgt       = (const float*)d_in[0];
    const float* memory    = (const float*)d_in[1];
    const float* queries   = (const float*)d_in[2];
    const float* wk        = (const float*)d_in[3];
    const float* in_proj_w = (const float*)d_in[4];
    const float* in_proj_b = (const float*)d_in[5];
    const float* out_proj_w= (const float*)d_in[6];
    const float* out_proj_b= (const float*)d_in[7];
    const float* lin1_w    = (const float*)d_in[8];
    const float* lin1_b    = (const float*)d_in[9];
    const float* lin2_w    = (const float*)d_in[10];
    const float* lin2_b    = (const float*)d_in[11];
    const float* ln1_g     = (const float*)d_in[12];
    const float* ln1_b     = (const float*)d_in[13];
    const float* ln2_g     = (const float*)d_in[14];
    const float* ln2_b     = (const float*)d_in[15];
    const float* ln3_g     = (const float*)d_in[16];
    const float* ln3_b     = (const float*)d_in[17];

    char* w = (char*)d_ws;
    float* qeff  = (float*)(w + 0);
    float* pbuf  = (float*)(w + 20480);
    float* mixed = (float*)(w + 872448);
    u16* y1  = (u16*)(w + 2969600);
    u16* qb  = (u16*)(w + 19746816);
    u16* kvb = (u16*)(w + 36524032);   // 8.4MB head-major KV
    u16* ob  = (u16*)(w + 44912640);
    // pre-attention residents of the ob region (dead before attn writes ob):
    u16* ipwb = (u16*)(w + 44912640);  // in_proj_w bf16 [1536*512]
    u16* memb = (u16*)(w + 46485504);  // memory bf16 [4096*512]
    // post-attention residents of the kvb region (kvb dead after attn):
    u16* opwb = (u16*)(w + 36524032);  // out_proj_w bf16 [512*512]
    u16* l1wb = (u16*)(w + 37048320);  // lin1_w bf16 [2048*512]
    u16* l2wb = (u16*)(w + 39145472);  // lin2_w bf16 [512*2048]
    u16* t1 = qb;  // out_proj result (qb dead after attention)
    u16* y2 = ob;  // LN2 out (ob = attn out, dead after out_proj)
    u16* hb = qb;  // FFN hidden chunk 4096x2048 (qb/t1 dead after LN2)
    u16* fb = y1;  // lin2 out (y1 dead after LN2)

    // ---- pre-attention conversions (memory + in_proj_w, fused) ----
    cvt2_kernel<<<2816, 256, 0, stream>>>(memory, in_proj_w, memb, ipwb);

    // ---- QA block ----
    qeff_kernel<<<1, 512, 0, stream>>>(queries, qeff);
    p_kernel<<<BB * (TT / 4), 256, 0, stream>>>(tgt, qeff, pbuf);
    winmix_kernel<<<BB * NW, 256, 0, stream>>>(pbuf, wk, tgt, mixed);
    ln_qa_kernel<<<(TT * BB) / 4, 256, 0, stream>>>(tgt, mixed, ln1_g, ln1_b, y1);

    // ---- MHA ----
    gemm_lds<0, 4, 0><<<dim3(DD / 128, (TT * BB) / 128), 256, 0, stream>>>(y1, ipwb, in_proj_b, qb, TT * BB, DD, DD);
    gemm_np<0, 1><<<dim3(1024 / 64, (SS * BB) / 64), 256, 0, stream>>>(memb, ipwb + (size_t)DD * DD, in_proj_b + DD, kvb, SS * BB, 1024, DD);
    attn_wp<<<dim3(TT / 128, BB * HH), 256, 0, stream>>>(qb, kvb, ob);
    // kvb dead; convert remaining weights into its region (fused)
    cvt3_kernel<<<2304, 256, 0, stream>>>(out_proj_w, lin1_w, lin2_w, opwb, l1wb, l2wb);
    gemm_lds<0, 4, 0><<<dim3(DD / 128, (TT * BB) / 128), 256, 0, stream>>>(ob, opwb, out_proj_b, t1, TT * BB, DD, DD);
    ln_rows_kernel<u16><<<(TT * BB) / 4, 256, 0, stream>>>(y1, t1, ln2_g, ln2_b, y2);

    // ---- FFN (4 chunks of 4096 rows; hidden in qb region) ----
    for (int c = 0; c < 4; c++) {
        const u16* y2c = y2 + (size_t)c * 4096 * DD;
        u16* fbc = fb + (size_t)c * 4096 * DD;
        gemm_lds<1, 4, 0><<<dim3(DFF / 128, 4096 / 128), 256, 0, stream>>>(y2c, l1wb, lin1_b, hb, 4096, DFF, DD);
        gemm_np<0, 0><<<dim3(DD / 64, 4096 / 64), 256, 0, stream>>>(hb, l2wb, lin2_b, fbc, 4096, DD, DFF);
    }
    ln_rows_kernel<float><<<(TT * BB) / 4, 256, 0, stream>>>(y2, fb, ln3_g, ln3_b, (float*)d_out);
}

// Round 7
// 526.329 us; speedup vs baseline: 1.1427x; 1.0137x over previous
//
#include <hip/hip_runtime.h>

// TransformerDecoderLayerQaN — MI355X round 13.
// R13 = R12 + xcd_remap in gemm_np ONLY (isolated T1 test): group the 8/16
// x-blocks sharing an A row-panel onto one XCD -> panel fetched once to that
// XCD's L2 (R12 measured lin2 FETCH 66.6MB = A re-fetched 8x from HBM across
// XCDs; W stays L3-hot). gemm_np grids (8,64) and (16,64) satisfy gy%8==0.
// Everything else R12-exact (R8 gemm_lds, R11 attn, fused cvt/winmix).
//
// ws layout (total 61,689,856 B — same envelope):
//   qeff  f32 [10*512]   @ 0
//   p     f32 [B*NQ*T]   @ 20480
//   mixed f32 [B*NW*D]   @ 872448
//   y1    bf16 [T*B*D]   @ 2969600    (reused: fb = lin2 out)
//   qb    bf16 [T*B*D]   @ 19746816   (reused: t1 = out_proj out; hb = FFN hidden)
//   kvb   bf16 [2][B][H][S][64] @ 36524032  (K part 0, V part 1; 8.4MB)
//     post-attn reuse: opwb @36524032, l1wb @37048320, l2wb @39145472
//   ob    bf16 [T*B*D]   @ 44912640   (reused: y2 = LN2 out)
//     pre-attn reuse: ipwb bf16[1536*512] @44912640, memb bf16[4096*512] @46485504

typedef unsigned short u16;
typedef unsigned int u32;
typedef short short8_t __attribute__((ext_vector_type(8)));
typedef float f32x4 __attribute__((ext_vector_type(4)));

#define TT 2048
#define BB 8
#define SS 512
#define DD 512
#define HH 8
#define DH 64
#define DFF 2048
#define NQ 10
#define WW 16
#define NW 128
#define KVPART 2097152   // elems per K / V part: B*H*S*DH = 8*8*512*64

__device__ __forceinline__ float b2f(u16 u) {
    return __uint_as_float(((unsigned int)u) << 16);
}
__device__ __forceinline__ u16 f2b(float f) {
    unsigned int x = __float_as_uint(f);
    unsigned int r = x + 0x7FFFu + ((x >> 16) & 1u);
    return (u16)(r >> 16);
}
__device__ __forceinline__ u32 cvt_pk_bf16(float lo, float hi) {
    u32 r;
    asm volatile("v_cvt_pk_bf16_f32 %0, %1, %2" : "=v"(r) : "v"(lo), "v"(hi));
    return r;
}
__device__ __forceinline__ float wave_sum(float v) {
    #pragma unroll
    for (int o = 32; o > 0; o >>= 1) v += __shfl_xor(v, o, 64);
    return v;
}
__device__ __forceinline__ float wave_max(float v) {
    #pragma unroll
    for (int o = 32; o > 0; o >>= 1) v = fmaxf(v, __shfl_xor(v, o, 64));
    return v;
}
__device__ __forceinline__ void load4(const u16* p, float* v) {
    ushort4 t = *(const ushort4*)p;
    v[0] = b2f(t.x); v[1] = b2f(t.y); v[2] = b2f(t.z); v[3] = b2f(t.w);
}
__device__ __forceinline__ void load4(const float* p, float* v) {
    float4 t = *(const float4*)p;
    v[0] = t.x; v[1] = t.y; v[2] = t.z; v[3] = t.w;
}
__device__ __forceinline__ void st1(u16* p, float v) { *p = f2b(v); }
__device__ __forceinline__ void st1(float* p, float v) { *p = v; }

// async global->LDS, 16B per lane; lds dest = wave-uniform base + lane*16
__device__ __forceinline__ void async16(const u16* g, u16* l) {
    __builtin_amdgcn_global_load_lds((const __attribute__((address_space(1))) u32*)g,
                                     (__attribute__((address_space(3))) u32*)l, 16, 0, 0);
}

// reuse-grouped XCD swizzle: flat%8 = XCD (dispatch round-robin); all gx
// col-blocks of a y-panel get the same flat%8 -> same XCD L2. Requires gy%8==0.
__device__ __forceinline__ void xcd_remap(int& bx, int& by) {
    int flat = blockIdx.y * gridDim.x + blockIdx.x;
    int xcd = flat & 7;
    int j = flat >> 3;
    by = xcd * ((int)gridDim.y >> 3) + j / (int)gridDim.x;
    bx = j % (int)gridDim.x;
}

// ---------------- fused f32 -> bf16 converts ----------------
__device__ __forceinline__ void cvt_block(const float* s, u16* d, int base) {
    int i = base + threadIdx.x * 4;
    float4 v = *(const float4*)(s + i);
    ushort4 o;
    o.x = f2b(v.x); o.y = f2b(v.y); o.z = f2b(v.z); o.w = f2b(v.w);
    *(ushort4*)(d + i) = o;
}

// memory (2,097,152 f32 -> 2048 blocks) + in_proj_w (786,432 -> 768 blocks)
__global__ __launch_bounds__(256) void cvt2_kernel(const float* __restrict__ s0,
                                                   const float* __restrict__ s1,
                                                   u16* __restrict__ d0,
                                                   u16* __restrict__ d1) {
    int bid = blockIdx.x;
    if (bid < 2048) cvt_block(s0, d0, bid * 1024);
    else            cvt_block(s1, d1, (bid - 2048) * 1024);
}

// out_proj_w (262,144 -> 256) + lin1_w (1,048,576 -> 1024) + lin2_w (1024)
__global__ __launch_bounds__(256) void cvt3_kernel(const float* __restrict__ s0,
                                                   const float* __restrict__ s1,
                                                   const float* __restrict__ s2,
                                                   u16* __restrict__ d0,
                                                   u16* __restrict__ d1,
                                                   u16* __restrict__ d2) {
    int bid = blockIdx.x;
    if (bid < 256)       cvt_block(s0, d0, bid * 1024);
    else if (bid < 1280) cvt_block(s1, d1, (bid - 256) * 1024);
    else                 cvt_block(s2, d2, (bid - 1280) * 1024);
}

// ---------------- QA block ----------------
__global__ __launch_bounds__(512) void qeff_kernel(const float* __restrict__ queries,
                                                   float* __restrict__ qeff) {
    int d = threadIdx.x;
    const float KS = 0.0055242717280199026f; // 1/(8*sqrt(512))
    for (int n = 0; n < NQ; n++) {
        float v = queries[n * DD + d];
        float ss = wave_sum(v * v);
        float norm = sqrtf(ss);
        qeff[n * DD + d] = v / (norm + 1e-6f) * KS;
    }
}

__global__ __launch_bounds__(256) void p_kernel(const float* __restrict__ x,
                                                const float* __restrict__ qeff,
                                                float* __restrict__ p) {
    __shared__ float qe[NQ * DD];
    for (int i = threadIdx.x; i < NQ * DD; i += 256) qe[i] = qeff[i];
    __syncthreads();
    int b = blockIdx.x >> 9;
    int t = ((blockIdx.x & 511) << 2) + (threadIdx.x >> 6);
    int lane = threadIdx.x & 63;
    const float* xr = x + ((size_t)t * BB + b) * DD;
    float acc[NQ];
    #pragma unroll
    for (int n = 0; n < NQ; n++) acc[n] = 0.f;
    #pragma unroll
    for (int c = 0; c < 8; c++) {
        int d = c * 64 + lane;
        float xv = xr[d];
        #pragma unroll
        for (int n = 0; n < NQ; n++) acc[n] += xv * qe[n * DD + d];
    }
    #pragma unroll
    for (int n = 0; n < NQ; n++) {
        float s = wave_sum(acc[n]);
        if (lane == 0) p[((size_t)(b * NQ + n)) * TT + t] = s;
    }
}

// fused win + mix: wave 0 computes the 48 combined softmax weights, then all
// 256 threads do the weighted row mix.
__global__ __launch_bounds__(256) void winmix_kernel(const float* __restrict__ p,
                                                     const float* __restrict__ wk,
                                                     const float* __restrict__ x,
                                                     float* __restrict__ mixed) {
    __shared__ float As[48];
    int id = blockIdx.x;
    int b = id >> 7, m = id & 127;
    if (threadIdx.x < 64) {
        int j = threadIdx.x;
        int tj = (m - 1) * WW + j;
        bool valid = (j < 48) && (tj >= 0) && (tj < TT);
        float acc = 0.f;
        for (int n = 0; n < NQ; n++) {
            float v = valid ? p[((size_t)(b * NQ + n)) * TT + tj] : -1e30f;
            float mx = wave_max(v);
            float e = valid ? __expf(v - mx) : 0.f;
            float s = wave_sum(e);
            acc += wk[n] * (e / s);
        }
        if (j < 48) As[j] = acc;
    }
    __syncthreads();
    int d0 = threadIdx.x, d1 = threadIdx.x + 256;
    float a0 = 0.f, a1 = 0.f;
    int tb = (m - 1) * WW;
    for (int j = 0; j < 48; j++) {
        int t = tb + j;
        if ((unsigned)t < (unsigned)TT) {
            float aj = As[j];
            const float* xr = x + ((size_t)t * BB + b) * DD;
            a0 += aj * xr[d0];
            a1 += aj * xr[d1];
        }
    }
    mixed[(size_t)id * DD + d0] = a0;
    mixed[(size_t)id * DD + d1] = a1;
}

__global__ __launch_bounds__(256) void ln_qa_kernel(const float* __restrict__ a,
                                                    const float* __restrict__ mixed,
                                                    const float* __restrict__ g,
                                                    const float* __restrict__ bt,
                                                    u16* __restrict__ out) {
    int r = blockIdx.x * 4 + (threadIdx.x >> 6); // r = t*B+b
    int lane = threadIdx.x & 63;
    int t = r >> 3, b = r & 7;
    const float* ar = a + (size_t)r * DD;
    const float* mr = mixed + ((size_t)(b * NW + (t >> 4))) * DD;
    int d0 = lane * 8;
    float av[8], mv[8], gg[8], bb[8];
    load4(ar + d0, av); load4(ar + d0 + 4, av + 4);
    load4(mr + d0, mv); load4(mr + d0 + 4, mv + 4);
    load4(g + d0, gg);  load4(g + d0 + 4, gg + 4);
    load4(bt + d0, bb); load4(bt + d0 + 4, bb + 4);
    float v[8];
    float s = 0.f, s2 = 0.f;
    #pragma unroll
    for (int u = 0; u < 8; u++) { v[u] = av[u] + mv[u]; s += v[u]; s2 += v[u] * v[u]; }
    s = wave_sum(s); s2 = wave_sum(s2);
    float mu = s * (1.f / DD);
    float var = s2 * (1.f / DD) - mu * mu;
    float rs = rsqrtf(var + 1e-5f);
    #pragma unroll
    for (int u = 0; u < 8; u++) out[(size_t)r * DD + d0 + u] = f2b((v[u] - mu) * rs * gg[u] + bb[u]);
}

template <typename OT>
__global__ __launch_bounds__(256) void ln_rows_kernel(const u16* __restrict__ a,
                                                      const u16* __restrict__ bsrc,
                                                      const float* __restrict__ g,
                                                      const float* __restrict__ bt,
                                                      OT* __restrict__ out) {
    int r = blockIdx.x * 4 + (threadIdx.x >> 6);
    int lane = threadIdx.x & 63;
    const u16* ar = a + (size_t)r * DD;
    const u16* br = bsrc + (size_t)r * DD;
    int d0 = lane * 8;
    float av[8], cv[8], gg[8], bb[8];
    load4(ar + d0, av); load4(ar + d0 + 4, av + 4);
    load4(br + d0, cv); load4(br + d0 + 4, cv + 4);
    load4(g + d0, gg);  load4(g + d0 + 4, gg + 4);
    load4(bt + d0, bb); load4(bt + d0 + 4, bb + 4);
    float v[8];
    float s = 0.f, s2 = 0.f;
    #pragma unroll
    for (int u = 0; u < 8; u++) { v[u] = av[u] + cv[u]; s += v[u]; s2 += v[u] * v[u]; }
    s = wave_sum(s); s2 = wave_sum(s2);
    float mu = s * (1.f / DD);
    float var = s2 * (1.f / DD) - mu * mu;
    float rs = rsqrtf(var + 1e-5f);
    #pragma unroll
    for (int u = 0; u < 8; u++) st1(out + (size_t)r * DD + d0 + u, (v[u] - mu) * rs * gg[u] + bb[u]);
}

// ---------------- MFMA GEMM, double-buffered global_load_lds (R8-exact) ----------------
// C = act(A[M,K] @ W[N,K]^T + bias). BM = MT*32, BN=128, BK=32, 4 waves (2x2).
template <int RELU, int MT, int KV>
__global__ __launch_bounds__(256) void gemm_lds(const u16* __restrict__ A,
                                                const u16* __restrict__ W,
                                                const float* __restrict__ bias,
                                                u16* __restrict__ C,
                                                int M, int N, int K) {
    constexpr int BM = MT * 32;
    constexpr int NIA = BM / 64;   // A DMA insts per wave
    __shared__ u16 As[2][BM * 32];
    __shared__ u16 Bs[2][128 * 32];
    int tid = threadIdx.x;
    int w = tid >> 6, lane = tid & 63;
    int n16 = lane & 15, quad = lane >> 4;
    int m0 = blockIdx.y * BM, n0 = blockIdx.x * 128;
    int wm16 = (w >> 1) * MT;       // m-block base (16-row units) for frags
    int wn = (w & 1) * 64;

    const u16* gA[NIA];
    u16* lA[NIA];
    #pragma unroll
    for (int i = 0; i < NIA; i++) {
        int s = (w * NIA + i) * 64 + lane;
        int mb = s >> 6, kseg = (s >> 4) & 3, m = s & 15;
        gA[i] = A + (size_t)(m0 + mb * 16 + m) * K + kseg * 8;
        lA[i] = &As[0][(size_t)((w * NIA + i) * 64) * 8];
    }
    const u16* gB[2];
    u16* lB[2];
    #pragma unroll
    for (int i = 0; i < 2; i++) {
        int s = (w * 2 + i) * 64 + lane;
        int nb = s >> 6, kseg = (s >> 4) & 3, n = s & 15;
        gB[i] = W + (size_t)(n0 + nb * 16 + n) * K + kseg * 8;
        lB[i] = &Bs[0][(size_t)((w * 2 + i) * 64) * 8];
    }

    f32x4 acc[MT][4];
    #pragma unroll
    for (int i = 0; i < MT; i++)
        #pragma unroll
        for (int j = 0; j < 4; j++) acc[i][j] = (f32x4){0.f, 0.f, 0.f, 0.f};

    const int nk = K >> 5;
    // prologue: stage tile 0 into buffer 0
    #pragma unroll
    for (int i = 0; i < NIA; i++) async16(gA[i], lA[i]);
    #pragma unroll
    for (int i = 0; i < 2; i++) async16(gB[i], lB[i]);
    __syncthreads();

    for (int t = 0; t < nk; t++) {
        int cur = t & 1;
        if (t + 1 < nk) {
            int nxt = cur ^ 1;
            #pragma unroll
            for (int i = 0; i < NIA; i++) async16(gA[i] + (t + 1) * 32, lA[i] + nxt * (BM * 32));
            #pragma unroll
            for (int i = 0; i < 2; i++) async16(gB[i] + (t + 1) * 32, lB[i] + nxt * 4096);
        }
        const u16* Ac = &As[cur][0];
        const u16* Bc = &Bs[cur][0];
        short8_t af[MT], bf[4];
        #pragma unroll
        for (int im = 0; im < MT; im++)
            af[im] = *(const short8_t*)(Ac + (size_t)((wm16 + im) * 64 + lane) * 8);
        #pragma unroll
        for (int in = 0; in < 4; in++)
            bf[in] = *(const short8_t*)(Bc + (size_t)(((w & 1) * 4 + in) * 64 + lane) * 8);
        #pragma unroll
        for (int im = 0; im < MT; im++)
            #pragma unroll
            for (int in = 0; in < 4; in++)
                acc[im][in] = __builtin_amdgcn_mfma_f32_16x16x32_bf16(af[im], bf[in], acc[im][in], 0, 0, 0);
        __syncthreads();   // drains next-tile DMA; all waves done reading cur
    }

    float bia[4];
    #pragma unroll
    for (int in = 0; in < 4; in++) bia[in] = bias[n0 + wn + in * 16 + n16];
    #pragma unroll
    for (int im = 0; im < MT; im++) {
        #pragma unroll
        for (int r = 0; r < 4; r++) {
            int row = m0 + (wm16 + im) * 16 + quad * 4 + r;
            #pragma unroll
            for (int in = 0; in < 4; in++) {
                float v = acc[im][in][r] + bia[in];
                if (RELU) v = fmaxf(v, 0.f);
                if (KV) {
                    int col = n0 + wn + in * 16 + n16;
                    int part = col >> 9, h = (col >> 6) & 7, d = col & 63;
                    int s = row >> 3, bq = row & 7;
                    C[(size_t)part * KVPART + ((size_t)(bq * HH + h) * SS + s) * DH + d] = f2b(v);
                } else {
                    C[(size_t)row * N + n0 + wn + in * 16 + n16] = f2b(v);
                }
            }
        }
    }
}

// ---------------- narrow-N MFMA GEMM, 2-deep pipelined + XCD-grouped ----------------
// BM=64, BN=64, BK=32; 4 waves as 2m x 2n (each wave 2x2 frags). 3 LDS
// buffers; counted s_waitcnt vmcnt(2) + raw s_barrier. xcd_remap groups all
// gx col-blocks of an A row-panel on ONE XCD -> panel fetched once to L2
// (R12: lin2 A re-fetched 8x from HBM, FETCH 66.6MB).
template <int RELU, int KV>
__global__ __launch_bounds__(256) void gemm_np(const u16* __restrict__ A,
                                               const u16* __restrict__ W,
                                               const float* __restrict__ bias,
                                               u16* __restrict__ C,
                                               int M, int N, int K) {
    __shared__ u16 As[3][64 * 32];
    __shared__ u16 Bs[3][64 * 32];
    int tid = threadIdx.x;
    int w = tid >> 6, lane = tid & 63;
    int n16 = lane & 15, quad = lane >> 4;
    int bx, by;
    xcd_remap(bx, by);
    int m0 = by * 64, n0 = bx * 64;
    int wm16 = (w >> 1) * 2;        // m-unit base for frags
    int wn = (w & 1) * 32;

    const u16* gA0 = A + (size_t)(m0 + w * 16 + n16) * K + quad * 8;
    const u16* gB0 = W + (size_t)(n0 + w * 16 + n16) * K + quad * 8;

    f32x4 acc[2][2];
    #pragma unroll
    for (int i = 0; i < 2; i++)
        #pragma unroll
        for (int j = 0; j < 2; j++) acc[i][j] = (f32x4){0.f, 0.f, 0.f, 0.f};

    const int nk = K >> 5;
    // prologue: stage tiles 0 and 1
    async16(gA0, &As[0][w * 512]);
    async16(gB0, &Bs[0][w * 512]);
    async16(gA0 + 32, &As[1][w * 512]);
    async16(gB0 + 32, &Bs[1][w * 512]);

    int cur = 0;
    for (int t = 0; t < nk; t++) {
        if (t + 1 < nk) {
            __asm__ volatile("s_waitcnt vmcnt(2)" ::: "memory");
        } else {
            __asm__ volatile("s_waitcnt vmcnt(0)" ::: "memory");
        }
        __builtin_amdgcn_s_barrier();
        __builtin_amdgcn_sched_barrier(0);
        if (t + 2 < nk) {
            int nx2 = cur + 2; if (nx2 >= 3) nx2 -= 3;
            async16(gA0 + (t + 2) * 32, &As[nx2][w * 512]);
            async16(gB0 + (t + 2) * 32, &Bs[nx2][w * 512]);
        }
        const u16* Ac = &As[cur][0];
        const u16* Bc = &Bs[cur][0];
        short8_t af[2], bf[2];
        #pragma unroll
        for (int im = 0; im < 2; im++)
            af[im] = *(const short8_t*)(Ac + (size_t)((wm16 + im) * 64 + lane) * 8);
        #pragma unroll
        for (int in = 0; in < 2; in++)
            bf[in] = *(const short8_t*)(Bc + (size_t)(((w & 1) * 2 + in) * 64 + lane) * 8);
        #pragma unroll
        for (int im = 0; im < 2; im++)
            #pragma unroll
            for (int in = 0; in < 2; in++)
                acc[im][in] = __builtin_amdgcn_mfma_f32_16x16x32_bf16(af[im], bf[in], acc[im][in], 0, 0, 0);
        __asm__ volatile("s_waitcnt lgkmcnt(0)" ::: "memory");
        cur = (cur == 2) ? 0 : cur + 1;
    }

    float bia[2];
    #pragma unroll
    for (int in = 0; in < 2; in++) bia[in] = bias[n0 + wn + in * 16 + n16];
    #pragma unroll
    for (int im = 0; im < 2; im++) {
        #pragma unroll
        for (int r = 0; r < 4; r++) {
            int row = m0 + (wm16 + im) * 16 + quad * 4 + r;
            #pragma unroll
            for (int in = 0; in < 2; in++) {
                float v = acc[im][in][r] + bia[in];
                if (RELU) v = fmaxf(v, 0.f);
                if (KV) {
                    int col = n0 + wn + in * 16 + n16;
                    int part = col >> 9, h = (col >> 6) & 7, d = col & 63;
                    int s = row >> 3, bq = row & 7;
                    C[(size_t)part * KVPART + ((size_t)(bq * HH + h) * SS + s) * DH + d] = f2b(v);
                } else {
                    C[(size_t)row * N + n0 + wn + in * 16 + n16] = f2b(v);
                }
            }
        }
    }
}

// ---------------- MFMA flash attention, swapped-QK in-register P (R11) ----------------
__global__ __launch_bounds__(256) void attn_wp(const u16* __restrict__ qb,
                                               const u16* __restrict__ kvb,
                                               u16* __restrict__ ob) {
    __shared__ u16 Kb[2][2048];        // fragment order, 4KB per buffer
    __shared__ u16 Vt[2][64][40];      // V^T [d][pos], stride 40 (2-way free)
    int tid = threadIdx.x;
    int w = tid >> 6, lane = tid & 63;
    int n16 = lane & 15, quad = lane >> 4, q8 = quad * 8;
    int xb, bh;
    xcd_remap(xb, bh);
    int b = bh >> 3, h = bh & 7;
    int q0 = xb * 128 + w * 32;

    short8_t aq[2][2];
    #pragma unroll
    for (int qt = 0; qt < 2; qt++) {
        const u16* qrow = qb + ((size_t)(q0 + qt * 16 + n16) * BB + b) * DD + h * DH;
        aq[qt][0] = *(const short8_t*)(qrow + q8);
        aq[qt][1] = *(const short8_t*)(qrow + 32 + q8);
    }

    const u16* kbase = kvb + (size_t)(b * HH + h) * (SS * DH);
    const u16* vbase = kvb + (size_t)KVPART + (size_t)(b * HH + h) * (SS * DH);

    // K DMA: wave w stages frag f=w (nt = w>>1, kh = w&1).
    const u16* gK = kbase + (size_t)((w >> 1) * 16 + n16) * DH + (w & 1) * 32 + q8;

    // V staging under sigma: lane owns positions {2m, 2m+1} (m = lane&15),
    // holding keys {key0, key0+1}: key0 = b2<2 ? 4a+2b2 : 16+4a+2(b2-2).
    int m = lane & 15;
    int a2 = m >> 2, b2 = m & 3;
    int key0 = (b2 < 2) ? (4 * a2 + 2 * b2) : (16 + 4 * a2 + 2 * (b2 - 2));
    int kp2 = m * 2;
    int vd = w * 16 + quad * 4;
    const u16* gV = vbase + (size_t)key0 * DH + vd;

    float lsum[2] = {0.f, 0.f};
    f32x4 Oa[2][4];
    #pragma unroll
    for (int qt = 0; qt < 2; qt++)
        #pragma unroll
        for (int ot = 0; ot < 4; ot++) Oa[qt][ot] = (f32x4){0.f, 0.f, 0.f, 0.f};

    union VU { ushort4 q; u16 h[4]; };
    union PU { u32 wd[4]; short8_t s8; };

    // ---- stage chunk 0 ----
    {
        async16(gK, &Kb[0][w * 512]);
        VU va, vb2;
        va.q  = *(const ushort4*)(gV);
        vb2.q = *(const ushort4*)(gV + DH);
        #pragma unroll
        for (int u = 0; u < 4; u++)
            *(u32*)&Vt[0][vd + u][kp2] = (u32)va.h[u] | ((u32)vb2.h[u] << 16);
    }
    __syncthreads();

    for (int c = 0; c < 16; c++) {
        int cur = c & 1, nxt = cur ^ 1;

        // ---- prefetch chunk c+1 (issue loads; consume after compute) ----
        VU va, vb2;
        if (c < 15) {
            const u16* gVc = gV + (size_t)(c + 1) * 32 * DH;
            va.q  = *(const ushort4*)(gVc);
            vb2.q = *(const ushort4*)(gVc + DH);
            async16(gK + (size_t)(c + 1) * 32 * DH, &Kb[nxt][w * 512]);
        }

        short8_t bk0 = *(const short8_t*)&Kb[cur][0 * 512 + lane * 8];
        short8_t bk1 = *(const short8_t*)&Kb[cur][1 * 512 + lane * 8];
        short8_t bk2 = *(const short8_t*)&Kb[cur][2 * 512 + lane * 8];
        short8_t bk3 = *(const short8_t*)&Kb[cur][3 * 512 + lane * 8];

        #pragma unroll
        for (int qt = 0; qt < 2; qt++) {
            // swapped QK^T: sc[nt] = K_nt * Q  -> D[key=quad*4+r][q=n16]
            f32x4 s0 = (f32x4){0.f, 0.f, 0.f, 0.f};
            s0 = __builtin_amdgcn_mfma_f32_16x16x32_bf16(bk0, aq[qt][0], s0, 0, 0, 0);
            s0 = __builtin_amdgcn_mfma_f32_16x16x32_bf16(bk1, aq[qt][1], s0, 0, 0, 0);
            f32x4 s1 = (f32x4){0.f, 0.f, 0.f, 0.f};
            s1 = __builtin_amdgcn_mfma_f32_16x16x32_bf16(bk2, aq[qt][0], s1, 0, 0, 0);
            s1 = __builtin_amdgcn_mfma_f32_16x16x32_bf16(bk3, aq[qt][1], s1, 0, 0, 0);

            // fixed-max softmax, all in registers
            float p0 = __expf(s0[0] * 0.125f - 8.0f);
            float p1 = __expf(s0[1] * 0.125f - 8.0f);
            float p2 = __expf(s0[2] * 0.125f - 8.0f);
            float p3 = __expf(s0[3] * 0.125f - 8.0f);
            float p4 = __expf(s1[0] * 0.125f - 8.0f);
            float p5 = __expf(s1[1] * 0.125f - 8.0f);
            float p6 = __expf(s1[2] * 0.125f - 8.0f);
            float p7 = __expf(s1[3] * 0.125f - 8.0f);
            lsum[qt] += ((p0 + p1) + (p2 + p3)) + ((p4 + p5) + (p6 + p7));

            PU pu;
            pu.wd[0] = cvt_pk_bf16(p0, p1);
            pu.wd[1] = cvt_pk_bf16(p2, p3);
            pu.wd[2] = cvt_pk_bf16(p4, p5);
            pu.wd[3] = cvt_pk_bf16(p6, p7);

            // O += P @ V (A = P in-register, B = V from sigma-ordered Vt)
            #pragma unroll
            for (int ot = 0; ot < 4; ot++) {
                short8_t bv = *(const short8_t*)&Vt[cur][ot * 16 + n16][q8];
                Oa[qt][ot] = __builtin_amdgcn_mfma_f32_16x16x32_bf16(pu.s8, bv, Oa[qt][ot], 0, 0, 0);
            }
        }

        // ---- write prefetched V into Vt[nxt] ----
        if (c < 15) {
            #pragma unroll
            for (int u = 0; u < 4; u++)
                *(u32*)&Vt[nxt][vd + u][kp2] = (u32)va.h[u] | ((u32)vb2.h[u] << 16);
        }
        __syncthreads();   // drains my K-DMA (vmcnt0) + orders LDS across waves
    }

    #pragma unroll
    for (int qt = 0; qt < 2; qt++) {
        // lsum[qt] is partial for q=n16 over this quad's 8 keys; sum quads
        float l = lsum[qt];
        l += __shfl_xor(l, 16, 64);
        l += __shfl_xor(l, 32, 64);
        #pragma unroll
        for (int r = 0; r < 4; r++) {
            float lq = __shfl(l, quad * 4 + r, 64);   // l for q = quad*4+r
            float inv = 1.f / lq;
            int t = q0 + qt * 16 + quad * 4 + r;
            u16* orow = ob + ((size_t)t * BB + b) * DD + h * DH + n16;
            #pragma unroll
            for (int ot = 0; ot < 4; ot++) orow[ot * 16] = f2b(Oa[qt][ot][r] * inv);
        }
    }
}

// ---------------- host ----------------
extern "C" void kernel_launch(void* const* d_in, const int* in_sizes, int n_in,
                              void* d_out, int out_size, void* d_ws, size_t ws_size,
                              hipStream_t stream) {
    const float* tgt       = (const float*)d_in[0];
    const float* memory    = (const float*)d_in[1];
    const float* queries   = (const float*)d_in[2];
    const float* wk        = (const float*)d_in[3];
    const float* in_proj_w = (const float*)d_in[4];
    const float* in_proj_b = (const float*)d_in[5];
    const float* out_proj_w= (const float*)d_in[6];
    const float* out_proj_b= (const float*)d_in[7];
    const float* lin1_w    = (const float*)d_in[8];
    const float* lin1_b    = (const float*)d_in[9];
    const float* lin2_w    = (const float*)d_in[10];
    const float* lin2_b    = (const float*)d_in[11];
    const float* ln1_g     = (const float*)d_in[12];
    const float* ln1_b     = (const float*)d_in[13];
    const float* ln2_g     = (const float*)d_in[14];
    const float* ln2_b     = (const float*)d_in[15];
    const float* ln3_g     = (const float*)d_in[16];
    const float* ln3_b     = (const float*)d_in[17];

    char* w = (char*)d_ws;
    float* qeff  = (float*)(w + 0);
    float* pbuf  = (float*)(w + 20480);
    float* mixed = (float*)(w + 872448);
    u16* y1  = (u16*)(w + 2969600);
    u16* qb  = (u16*)(w + 19746816);
    u16* kvb = (u16*)(w + 36524032);   // 8.4MB head-major KV
    u16* ob  = (u16*)(w + 44912640);
    // pre-attention residents of the ob region (dead before attn writes ob):
    u16* ipwb = (u16*)(w + 44912640);  // in_proj_w bf16 [1536*512]
    u16* memb = (u16*)(w + 46485504);  // memory bf16 [4096*512]
    // post-attention residents of the kvb region (kvb dead after attn):
    u16* opwb = (u16*)(w + 36524032);  // out_proj_w bf16 [512*512]
    u16* l1wb = (u16*)(w + 37048320);  // lin1_w bf16 [2048*512]
    u16* l2wb = (u16*)(w + 39145472);  // lin2_w bf16 [512*2048]
    u16* t1 = qb;  // out_proj result (qb dead after attention)
    u16* y2 = ob;  // LN2 out (ob = attn out, dead after out_proj)
    u16* hb = qb;  // FFN hidden chunk 4096x2048 (qb/t1 dead after LN2)
    u16* fb = y1;  // lin2 out (y1 dead after LN2)

    // ---- pre-attention conversions (memory + in_proj_w, fused) ----
    cvt2_kernel<<<2816, 256, 0, stream>>>(memory, in_proj_w, memb, ipwb);

    // ---- QA block ----
    qeff_kernel<<<1, 512, 0, stream>>>(queries, qeff);
    p_kernel<<<BB * (TT / 4), 256, 0, stream>>>(tgt, qeff, pbuf);
    winmix_kernel<<<BB * NW, 256, 0, stream>>>(pbuf, wk, tgt, mixed);
    ln_qa_kernel<<<(TT * BB) / 4, 256, 0, stream>>>(tgt, mixed, ln1_g, ln1_b, y1);

    // ---- MHA ----
    gemm_lds<0, 4, 0><<<dim3(DD / 128, (TT * BB) / 128), 256, 0, stream>>>(y1, ipwb, in_proj_b, qb, TT * BB, DD, DD);
    gemm_np<0, 1><<<dim3(1024 / 64, (SS * BB) / 64), 256, 0, stream>>>(memb, ipwb + (size_t)DD * DD, in_proj_b + DD, kvb, SS * BB, 1024, DD);
    attn_wp<<<dim3(TT / 128, BB * HH), 256, 0, stream>>>(qb, kvb, ob);
    // kvb dead; convert remaining weights into its region (fused)
    cvt3_kernel<<<2304, 256, 0, stream>>>(out_proj_w, lin1_w, lin2_w, opwb, l1wb, l2wb);
    gemm_lds<0, 4, 0><<<dim3(DD / 128, (TT * BB) / 128), 256, 0, stream>>>(ob, opwb, out_proj_b, t1, TT * BB, DD, DD);
    ln_rows_kernel<u16><<<(TT * BB) / 4, 256, 0, stream>>>(y1, t1, ln2_g, ln2_b, y2);

    // ---- FFN (4 chunks of 4096 rows; hidden in qb region) ----
    for (int c = 0; c < 4; c++) {
        const u16* y2c = y2 + (size_t)c * 4096 * DD;
        u16* fbc = fb + (size_t)c * 4096 * DD;
        gemm_lds<1, 4, 0><<<dim3(DFF / 128, 4096 / 128), 256, 0, stream>>>(y2c, l1wb, lin1_b, hb, 4096, DFF, DD);
        gemm_np<0, 0><<<dim3(DD / 64, 4096 / 64), 256, 0, stream>>>(hb, l2wb, lin2_b, fbc, 4096, DD, DFF);
    }
    ln_rows_kernel<float><<<(TT * BB) / 4, 256, 0, stream>>>(y2, fb, ln3_g, ln3_b, (float*)d_out);
}

// Round 8
// 472.828 us; speedup vs baseline: 1.2720x; 1.1132x over previous
//
#include <hip/hip_runtime.h>

// TransformerDecoderLayerQaN — MI355X round 14.
// R14 = R13 + ffn_fused: lin1+lin2 fused into one kernel using the R11
// swapped-operand structure (W1=K, W2=V, y2-rows=Q, hidden=keys, relu=softmax).
// Eliminates the 64MB hidden round-trip and the 8-dispatch chunk serialization
// (R13 FFN ~250us, step-serial-latency-bound per R12/R13 falsification).
// Per 64-row block: aq[16] y2-frags in registers; 64 chunks of 32 hidden;
// W1 via global_load_lds frag-order (dbuf), W2 via sigma-ordered cooperative
// transpose (issue-early/write-late); hidden P in-register via cvt_pk;
// acc[32] f32x4 = full 16x512 out per wave. LDS 152KB, 1 block/CU,
// launch_bounds(256,1). Everything else R13-exact.
//
// ws layout (total 61,689,856 B — same envelope):
//   qeff  f32 [10*512]   @ 0
//   p     f32 [B*NQ*T]   @ 20480
//   mixed f32 [B*NW*D]   @ 872448
//   y1    bf16 [T*B*D]   @ 2969600    (reused: fb = FFN out)
//   qb    bf16 [T*B*D]   @ 19746816   (reused: t1 = out_proj out)
//   kvb   bf16 [2][B][H][S][64] @ 36524032  (K part 0, V part 1; 8.4MB)
//     post-attn reuse: opwb @36524032, l1wb @37048320, l2wb @39145472
//   ob    bf16 [T*B*D]   @ 44912640   (reused: y2 = LN2 out)
//     pre-attn reuse: ipwb bf16[1536*512] @44912640, memb bf16[4096*512] @46485504

typedef unsigned short u16;
typedef unsigned int u32;
typedef short short8_t __attribute__((ext_vector_type(8)));
typedef float f32x4 __attribute__((ext_vector_type(4)));

#define TT 2048
#define BB 8
#define SS 512
#define DD 512
#define HH 8
#define DH 64
#define DFF 2048
#define NQ 10
#define WW 16
#define NW 128
#define KVPART 2097152   // elems per K / V part: B*H*S*DH = 8*8*512*64

__device__ __forceinline__ float b2f(u16 u) {
    return __uint_as_float(((unsigned int)u) << 16);
}
__device__ __forceinline__ u16 f2b(float f) {
    unsigned int x = __float_as_uint(f);
    unsigned int r = x + 0x7FFFu + ((x >> 16) & 1u);
    return (u16)(r >> 16);
}
__device__ __forceinline__ u32 cvt_pk_bf16(float lo, float hi) {
    u32 r;
    asm volatile("v_cvt_pk_bf16_f32 %0, %1, %2" : "=v"(r) : "v"(lo), "v"(hi));
    return r;
}
__device__ __forceinline__ float wave_sum(float v) {
    #pragma unroll
    for (int o = 32; o > 0; o >>= 1) v += __shfl_xor(v, o, 64);
    return v;
}
__device__ __forceinline__ float wave_max(float v) {
    #pragma unroll
    for (int o = 32; o > 0; o >>= 1) v = fmaxf(v, __shfl_xor(v, o, 64));
    return v;
}
__device__ __forceinline__ void load4(const u16* p, float* v) {
    ushort4 t = *(const ushort4*)p;
    v[0] = b2f(t.x); v[1] = b2f(t.y); v[2] = b2f(t.z); v[3] = b2f(t.w);
}
__device__ __forceinline__ void load4(const float* p, float* v) {
    float4 t = *(const float4*)p;
    v[0] = t.x; v[1] = t.y; v[2] = t.z; v[3] = t.w;
}
__device__ __forceinline__ void st1(u16* p, float v) { *p = f2b(v); }
__device__ __forceinline__ void st1(float* p, float v) { *p = v; }

// async global->LDS, 16B per lane; lds dest = wave-uniform base + lane*16
__device__ __forceinline__ void async16(const u16* g, u16* l) {
    __builtin_amdgcn_global_load_lds((const __attribute__((address_space(1))) u32*)g,
                                     (__attribute__((address_space(3))) u32*)l, 16, 0, 0);
}

// reuse-grouped XCD swizzle: flat%8 = XCD (dispatch round-robin); all gx
// col-blocks of a y-panel get the same flat%8 -> same XCD L2. Requires gy%8==0.
__device__ __forceinline__ void xcd_remap(int& bx, int& by) {
    int flat = blockIdx.y * gridDim.x + blockIdx.x;
    int xcd = flat & 7;
    int j = flat >> 3;
    by = xcd * ((int)gridDim.y >> 3) + j / (int)gridDim.x;
    bx = j % (int)gridDim.x;
}

// ---------------- fused f32 -> bf16 converts ----------------
__device__ __forceinline__ void cvt_block(const float* s, u16* d, int base) {
    int i = base + threadIdx.x * 4;
    float4 v = *(const float4*)(s + i);
    ushort4 o;
    o.x = f2b(v.x); o.y = f2b(v.y); o.z = f2b(v.z); o.w = f2b(v.w);
    *(ushort4*)(d + i) = o;
}

// memory (2,097,152 f32 -> 2048 blocks) + in_proj_w (786,432 -> 768 blocks)
__global__ __launch_bounds__(256) void cvt2_kernel(const float* __restrict__ s0,
                                                   const float* __restrict__ s1,
                                                   u16* __restrict__ d0,
                                                   u16* __restrict__ d1) {
    int bid = blockIdx.x;
    if (bid < 2048) cvt_block(s0, d0, bid * 1024);
    else            cvt_block(s1, d1, (bid - 2048) * 1024);
}

// out_proj_w (262,144 -> 256) + lin1_w (1,048,576 -> 1024) + lin2_w (1024)
__global__ __launch_bounds__(256) void cvt3_kernel(const float* __restrict__ s0,
                                                   const float* __restrict__ s1,
                                                   const float* __restrict__ s2,
                                                   u16* __restrict__ d0,
                                                   u16* __restrict__ d1,
                                                   u16* __restrict__ d2) {
    int bid = blockIdx.x;
    if (bid < 256)       cvt_block(s0, d0, bid * 1024);
    else if (bid < 1280) cvt_block(s1, d1, (bid - 256) * 1024);
    else                 cvt_block(s2, d2, (bid - 1280) * 1024);
}

// ---------------- QA block ----------------
__global__ __launch_bounds__(512) void qeff_kernel(const float* __restrict__ queries,
                                                   float* __restrict__ qeff) {
    int d = threadIdx.x;
    const float KS = 0.0055242717280199026f; // 1/(8*sqrt(512))
    for (int n = 0; n < NQ; n++) {
        float v = queries[n * DD + d];
        float ss = wave_sum(v * v);
        float norm = sqrtf(ss);
        qeff[n * DD + d] = v / (norm + 1e-6f) * KS;
    }
}

__global__ __launch_bounds__(256) void p_kernel(const float* __restrict__ x,
                                                const float* __restrict__ qeff,
                                                float* __restrict__ p) {
    __shared__ float qe[NQ * DD];
    for (int i = threadIdx.x; i < NQ * DD; i += 256) qe[i] = qeff[i];
    __syncthreads();
    int b = blockIdx.x >> 9;
    int t = ((blockIdx.x & 511) << 2) + (threadIdx.x >> 6);
    int lane = threadIdx.x & 63;
    const float* xr = x + ((size_t)t * BB + b) * DD;
    float acc[NQ];
    #pragma unroll
    for (int n = 0; n < NQ; n++) acc[n] = 0.f;
    #pragma unroll
    for (int c = 0; c < 8; c++) {
        int d = c * 64 + lane;
        float xv = xr[d];
        #pragma unroll
        for (int n = 0; n < NQ; n++) acc[n] += xv * qe[n * DD + d];
    }
    #pragma unroll
    for (int n = 0; n < NQ; n++) {
        float s = wave_sum(acc[n]);
        if (lane == 0) p[((size_t)(b * NQ + n)) * TT + t] = s;
    }
}

// fused win + mix: wave 0 computes the 48 combined softmax weights, then all
// 256 threads do the weighted row mix.
__global__ __launch_bounds__(256) void winmix_kernel(const float* __restrict__ p,
                                                     const float* __restrict__ wk,
                                                     const float* __restrict__ x,
                                                     float* __restrict__ mixed) {
    __shared__ float As[48];
    int id = blockIdx.x;
    int b = id >> 7, m = id & 127;
    if (threadIdx.x < 64) {
        int j = threadIdx.x;
        int tj = (m - 1) * WW + j;
        bool valid = (j < 48) && (tj >= 0) && (tj < TT);
        float acc = 0.f;
        for (int n = 0; n < NQ; n++) {
            float v = valid ? p[((size_t)(b * NQ + n)) * TT + tj] : -1e30f;
            float mx = wave_max(v);
            float e = valid ? __expf(v - mx) : 0.f;
            float s = wave_sum(e);
            acc += wk[n] * (e / s);
        }
        if (j < 48) As[j] = acc;
    }
    __syncthreads();
    int d0 = threadIdx.x, d1 = threadIdx.x + 256;
    float a0 = 0.f, a1 = 0.f;
    int tb = (m - 1) * WW;
    for (int j = 0; j < 48; j++) {
        int t = tb + j;
        if ((unsigned)t < (unsigned)TT) {
            float aj = As[j];
            const float* xr = x + ((size_t)t * BB + b) * DD;
            a0 += aj * xr[d0];
            a1 += aj * xr[d1];
        }
    }
    mixed[(size_t)id * DD + d0] = a0;
    mixed[(size_t)id * DD + d1] = a1;
}

__global__ __launch_bounds__(256) void ln_qa_kernel(const float* __restrict__ a,
                                                    const float* __restrict__ mixed,
                                                    const float* __restrict__ g,
                                                    const float* __restrict__ bt,
                                                    u16* __restrict__ out) {
    int r = blockIdx.x * 4 + (threadIdx.x >> 6); // r = t*B+b
    int lane = threadIdx.x & 63;
    int t = r >> 3, b = r & 7;
    const float* ar = a + (size_t)r * DD;
    const float* mr = mixed + ((size_t)(b * NW + (t >> 4))) * DD;
    int d0 = lane * 8;
    float av[8], mv[8], gg[8], bb[8];
    load4(ar + d0, av); load4(ar + d0 + 4, av + 4);
    load4(mr + d0, mv); load4(mr + d0 + 4, mv + 4);
    load4(g + d0, gg);  load4(g + d0 + 4, gg + 4);
    load4(bt + d0, bb); load4(bt + d0 + 4, bb + 4);
    float v[8];
    float s = 0.f, s2 = 0.f;
    #pragma unroll
    for (int u = 0; u < 8; u++) { v[u] = av[u] + mv[u]; s += v[u]; s2 += v[u] * v[u]; }
    s = wave_sum(s); s2 = wave_sum(s2);
    float mu = s * (1.f / DD);
    float var = s2 * (1.f / DD) - mu * mu;
    float rs = rsqrtf(var + 1e-5f);
    #pragma unroll
    for (int u = 0; u < 8; u++) out[(size_t)r * DD + d0 + u] = f2b((v[u] - mu) * rs * gg[u] + bb[u]);
}

template <typename OT>
__global__ __launch_bounds__(256) void ln_rows_kernel(const u16* __restrict__ a,
                                                      const u16* __restrict__ bsrc,
                                                      const float* __restrict__ g,
                                                      const float* __restrict__ bt,
                                                      OT* __restrict__ out) {
    int r = blockIdx.x * 4 + (threadIdx.x >> 6);
    int lane = threadIdx.x & 63;
    const u16* ar = a + (size_t)r * DD;
    const u16* br = bsrc + (size_t)r * DD;
    int d0 = lane * 8;
    float av[8], cv[8], gg[8], bb[8];
    load4(ar + d0, av); load4(ar + d0 + 4, av + 4);
    load4(br + d0, cv); load4(br + d0 + 4, cv + 4);
    load4(g + d0, gg);  load4(g + d0 + 4, gg + 4);
    load4(bt + d0, bb); load4(bt + d0 + 4, bb + 4);
    float v[8];
    float s = 0.f, s2 = 0.f;
    #pragma unroll
    for (int u = 0; u < 8; u++) { v[u] = av[u] + cv[u]; s += v[u]; s2 += v[u] * v[u]; }
    s = wave_sum(s); s2 = wave_sum(s2);
    float mu = s * (1.f / DD);
    float var = s2 * (1.f / DD) - mu * mu;
    float rs = rsqrtf(var + 1e-5f);
    #pragma unroll
    for (int u = 0; u < 8; u++) st1(out + (size_t)r * DD + d0 + u, (v[u] - mu) * rs * gg[u] + bb[u]);
}

// ---------------- MFMA GEMM, double-buffered global_load_lds (R8-exact) ----------------
// C = act(A[M,K] @ W[N,K]^T + bias). BM = MT*32, BN=128, BK=32, 4 waves (2x2).
template <int RELU, int MT, int KV>
__global__ __launch_bounds__(256) void gemm_lds(const u16* __restrict__ A,
                                                const u16* __restrict__ W,
                                                const float* __restrict__ bias,
                                                u16* __restrict__ C,
                                                int M, int N, int K) {
    constexpr int BM = MT * 32;
    constexpr int NIA = BM / 64;   // A DMA insts per wave
    __shared__ u16 As[2][BM * 32];
    __shared__ u16 Bs[2][128 * 32];
    int tid = threadIdx.x;
    int w = tid >> 6, lane = tid & 63;
    int n16 = lane & 15, quad = lane >> 4;
    int m0 = blockIdx.y * BM, n0 = blockIdx.x * 128;
    int wm16 = (w >> 1) * MT;       // m-block base (16-row units) for frags
    int wn = (w & 1) * 64;

    const u16* gA[NIA];
    u16* lA[NIA];
    #pragma unroll
    for (int i = 0; i < NIA; i++) {
        int s = (w * NIA + i) * 64 + lane;
        int mb = s >> 6, kseg = (s >> 4) & 3, m = s & 15;
        gA[i] = A + (size_t)(m0 + mb * 16 + m) * K + kseg * 8;
        lA[i] = &As[0][(size_t)((w * NIA + i) * 64) * 8];
    }
    const u16* gB[2];
    u16* lB[2];
    #pragma unroll
    for (int i = 0; i < 2; i++) {
        int s = (w * 2 + i) * 64 + lane;
        int nb = s >> 6, kseg = (s >> 4) & 3, n = s & 15;
        gB[i] = W + (size_t)(n0 + nb * 16 + n) * K + kseg * 8;
        lB[i] = &Bs[0][(size_t)((w * 2 + i) * 64) * 8];
    }

    f32x4 acc[MT][4];
    #pragma unroll
    for (int i = 0; i < MT; i++)
        #pragma unroll
        for (int j = 0; j < 4; j++) acc[i][j] = (f32x4){0.f, 0.f, 0.f, 0.f};

    const int nk = K >> 5;
    // prologue: stage tile 0 into buffer 0
    #pragma unroll
    for (int i = 0; i < NIA; i++) async16(gA[i], lA[i]);
    #pragma unroll
    for (int i = 0; i < 2; i++) async16(gB[i], lB[i]);
    __syncthreads();

    for (int t = 0; t < nk; t++) {
        int cur = t & 1;
        if (t + 1 < nk) {
            int nxt = cur ^ 1;
            #pragma unroll
            for (int i = 0; i < NIA; i++) async16(gA[i] + (t + 1) * 32, lA[i] + nxt * (BM * 32));
            #pragma unroll
            for (int i = 0; i < 2; i++) async16(gB[i] + (t + 1) * 32, lB[i] + nxt * 4096);
        }
        const u16* Ac = &As[cur][0];
        const u16* Bc = &Bs[cur][0];
        short8_t af[MT], bf[4];
        #pragma unroll
        for (int im = 0; im < MT; im++)
            af[im] = *(const short8_t*)(Ac + (size_t)((wm16 + im) * 64 + lane) * 8);
        #pragma unroll
        for (int in = 0; in < 4; in++)
            bf[in] = *(const short8_t*)(Bc + (size_t)(((w & 1) * 4 + in) * 64 + lane) * 8);
        #pragma unroll
        for (int im = 0; im < MT; im++)
            #pragma unroll
            for (int in = 0; in < 4; in++)
                acc[im][in] = __builtin_amdgcn_mfma_f32_16x16x32_bf16(af[im], bf[in], acc[im][in], 0, 0, 0);
        __syncthreads();   // drains next-tile DMA; all waves done reading cur
    }

    float bia[4];
    #pragma unroll
    for (int in = 0; in < 4; in++) bia[in] = bias[n0 + wn + in * 16 + n16];
    #pragma unroll
    for (int im = 0; im < MT; im++) {
        #pragma unroll
        for (int r = 0; r < 4; r++) {
            int row = m0 + (wm16 + im) * 16 + quad * 4 + r;
            #pragma unroll
            for (int in = 0; in < 4; in++) {
                float v = acc[im][in][r] + bia[in];
                if (RELU) v = fmaxf(v, 0.f);
                if (KV) {
                    int col = n0 + wn + in * 16 + n16;
                    int part = col >> 9, h = (col >> 6) & 7, d = col & 63;
                    int s = row >> 3, bq = row & 7;
                    C[(size_t)part * KVPART + ((size_t)(bq * HH + h) * SS + s) * DH + d] = f2b(v);
                } else {
                    C[(size_t)row * N + n0 + wn + in * 16 + n16] = f2b(v);
                }
            }
        }
    }
}

// ---------------- narrow-N MFMA GEMM, 2-deep pipelined + XCD-grouped ----------------
// Used for the KV projection (256-block case). BM=64, BN=64, BK=32.
template <int RELU, int KV>
__global__ __launch_bounds__(256) void gemm_np(const u16* __restrict__ A,
                                               const u16* __restrict__ W,
                                               const float* __restrict__ bias,
                                               u16* __restrict__ C,
                                               int M, int N, int K) {
    __shared__ u16 As[3][64 * 32];
    __shared__ u16 Bs[3][64 * 32];
    int tid = threadIdx.x;
    int w = tid >> 6, lane = tid & 63;
    int n16 = lane & 15, quad = lane >> 4;
    int bx, by;
    xcd_remap(bx, by);
    int m0 = by * 64, n0 = bx * 64;
    int wm16 = (w >> 1) * 2;        // m-unit base for frags
    int wn = (w & 1) * 32;

    const u16* gA0 = A + (size_t)(m0 + w * 16 + n16) * K + quad * 8;
    const u16* gB0 = W + (size_t)(n0 + w * 16 + n16) * K + quad * 8;

    f32x4 acc[2][2];
    #pragma unroll
    for (int i = 0; i < 2; i++)
        #pragma unroll
        for (int j = 0; j < 2; j++) acc[i][j] = (f32x4){0.f, 0.f, 0.f, 0.f};

    const int nk = K >> 5;
    // prologue: stage tiles 0 and 1
    async16(gA0, &As[0][w * 512]);
    async16(gB0, &Bs[0][w * 512]);
    async16(gA0 + 32, &As[1][w * 512]);
    async16(gB0 + 32, &Bs[1][w * 512]);

    int cur = 0;
    for (int t = 0; t < nk; t++) {
        if (t + 1 < nk) {
            __asm__ volatile("s_waitcnt vmcnt(2)" ::: "memory");
        } else {
            __asm__ volatile("s_waitcnt vmcnt(0)" ::: "memory");
        }
        __builtin_amdgcn_s_barrier();
        __builtin_amdgcn_sched_barrier(0);
        if (t + 2 < nk) {
            int nx2 = cur + 2; if (nx2 >= 3) nx2 -= 3;
            async16(gA0 + (t + 2) * 32, &As[nx2][w * 512]);
            async16(gB0 + (t + 2) * 32, &Bs[nx2][w * 512]);
        }
        const u16* Ac = &As[cur][0];
        const u16* Bc = &Bs[cur][0];
        short8_t af[2], bf[2];
        #pragma unroll
        for (int im = 0; im < 2; im++)
            af[im] = *(const short8_t*)(Ac + (size_t)((wm16 + im) * 64 + lane) * 8);
        #pragma unroll
        for (int in = 0; in < 2; in++)
            bf[in] = *(const short8_t*)(Bc + (size_t)(((w & 1) * 2 + in) * 64 + lane) * 8);
        #pragma unroll
        for (int im = 0; im < 2; im++)
            #pragma unroll
            for (int in = 0; in < 2; in++)
                acc[im][in] = __builtin_amdgcn_mfma_f32_16x16x32_bf16(af[im], bf[in], acc[im][in], 0, 0, 0);
        __asm__ volatile("s_waitcnt lgkmcnt(0)" ::: "memory");
        cur = (cur == 2) ? 0 : cur + 1;
    }

    float bia[2];
    #pragma unroll
    for (int in = 0; in < 2; in++) bia[in] = bias[n0 + wn + in * 16 + n16];
    #pragma unroll
    for (int im = 0; im < 2; im++) {
        #pragma unroll
        for (int r = 0; r < 4; r++) {
            int row = m0 + (wm16 + im) * 16 + quad * 4 + r;
            #pragma unroll
            for (int in = 0; in < 2; in++) {
                float v = acc[im][in][r] + bia[in];
                if (RELU) v = fmaxf(v, 0.f);
                if (KV) {
                    int col = n0 + wn + in * 16 + n16;
                    int part = col >> 9, h = (col >> 6) & 7, d = col & 63;
                    int s = row >> 3, bq = row & 7;
                    C[(size_t)part * KVPART + ((size_t)(bq * HH + h) * SS + s) * DH + d] = f2b(v);
                } else {
                    C[(size_t)row * N + n0 + wn + in * 16 + n16] = f2b(v);
                }
            }
        }
    }
}

// ---------------- fused FFN: out = relu(A@W1^T + b1) @ W2^T + b2 ----------------
// R11-attn structure: W1=K, W2=V, A-rows=Q, hidden=keys (64 chunks x 32).
// grid M/64 blocks, 4 waves x 16 rows. A rows in registers (aq[16] B-frags).
// Per chunk: W1 slice 32x512 via global_load_lds frag-order (dbuf); W2 slice
// 512x32 via sigma-ordered cooperative transpose (issue-early/write-late);
// swapped mfma(W1,A) -> hidden P in-register in sigma-slot layout; cvt_pk;
// 32 lin2 MFMAs accumulate the full 16x512 out (acc[32]).
__global__ __launch_bounds__(256, 1) void ffn_fused(const u16* __restrict__ A,
                                                    const u16* __restrict__ W1,
                                                    const float* __restrict__ b1,
                                                    const u16* __restrict__ W2,
                                                    const float* __restrict__ b2,
                                                    u16* __restrict__ Cout) {
    __shared__ u16 W1b[2][32 * 512];   // 32 hidden x 512 K, frag order (32KB each)
    __shared__ u16 Vt[2][512][40];     // W2^T sigma-order [out][pos] (40KB each)
    __shared__ float b1s[DFF];         // 8KB
    int tid = threadIdx.x;
    int w = tid >> 6, lane = tid & 63;
    int n16 = lane & 15, quad = lane >> 4, q8 = quad * 8;
    int m0 = blockIdx.x * 64;
    int row = m0 + w * 16 + n16;

    for (int i = tid; i < DFF; i += 256) b1s[i] = b1[i];

    // A rows -> registers (B-operand frags: lane holds col=n16(row), k at quad*8)
    short8_t aq[16];
    {
        const u16* ar = A + (size_t)row * DD + q8;
        #pragma unroll
        for (int ks = 0; ks < 16; ks++)
            aq[ks] = *(const short8_t*)(ar + ks * 32);
    }

    // W1 DMA: wave w stages frags f=w*8+i (nt=w>>1, ks=(w&1)*8+i)
    const u16* gW1 = W1 + (size_t)((w >> 1) * 16 + n16) * DD + ((w & 1) * 8) * 32 + q8;
    // W2 stager: thread covers o = i*32 + (tid>>3), hidden h4=(tid&7)*4
    int h4 = (tid & 7) * 4;
    int pos = (h4 < 16) ? ((h4 >> 2) << 3) : ((((h4 - 16) >> 2) << 3) + 4);
    const u16* gW2 = W2 + (size_t)(tid >> 3) * DFF + h4;

    f32x4 acc[32];
    #pragma unroll
    for (int ot = 0; ot < 32; ot++) acc[ot] = (f32x4){0.f, 0.f, 0.f, 0.f};

    union PU { u32 wd[4]; short8_t s8; };

    // ---- stage chunk 0 ----
    #pragma unroll
    for (int i = 0; i < 8; i++)
        async16(gW1 + i * 32, &W1b[0][(size_t)(w * 8 + i) * 512]);
    #pragma unroll
    for (int i = 0; i < 16; i++) {
        ushort4 v = *(const ushort4*)(gW2 + (size_t)i * 32 * DFF);
        *(ushort4*)&Vt[0][i * 32 + (tid >> 3)][pos] = v;
    }
    __syncthreads();

    for (int c = 0; c < 64; c++) {
        int cur = c & 1, nxt = cur ^ 1;

        // ---- prefetch chunk c+1 (W2 loads early; W1 DMA; writes after compute) ----
        ushort4 w2r[16];
        if (c < 63) {
            const u16* gW2c = gW2 + (size_t)(c + 1) * 32;
            #pragma unroll
            for (int i = 0; i < 16; i++)
                w2r[i] = *(const ushort4*)(gW2c + (size_t)i * 32 * DFF);
            const u16* gW1c = gW1 + (size_t)(c + 1) * 32 * DD;
            #pragma unroll
            for (int i = 0; i < 8; i++)
                async16(gW1c + i * 32, &W1b[nxt][(size_t)(w * 8 + i) * 512]);
        }

        // ---- lin1 (swapped): s[nt] = W1_nt @ A -> D[hidden=quad*4+r][row=n16] ----
        f32x4 s0 = (f32x4){0.f, 0.f, 0.f, 0.f};
        f32x4 s1 = (f32x4){0.f, 0.f, 0.f, 0.f};
        #pragma unroll
        for (int ks = 0; ks < 16; ks++) {
            short8_t f0 = *(const short8_t*)&W1b[cur][(size_t)ks * 512 + lane * 8];
            s0 = __builtin_amdgcn_mfma_f32_16x16x32_bf16(f0, aq[ks], s0, 0, 0, 0);
        }
        #pragma unroll
        for (int ks = 0; ks < 16; ks++) {
            short8_t f1 = *(const short8_t*)&W1b[cur][(size_t)(16 + ks) * 512 + lane * 8];
            s1 = __builtin_amdgcn_mfma_f32_16x16x32_bf16(f1, aq[ks], s1, 0, 0, 0);
        }

        // ---- bias + relu, all in registers ----
        float p0 = fmaxf(s0[0] + b1s[c * 32 + quad * 4 + 0], 0.f);
        float p1 = fmaxf(s0[1] + b1s[c * 32 + quad * 4 + 1], 0.f);
        float p2 = fmaxf(s0[2] + b1s[c * 32 + quad * 4 + 2], 0.f);
        float p3 = fmaxf(s0[3] + b1s[c * 32 + quad * 4 + 3], 0.f);
        float p4 = fmaxf(s1[0] + b1s[c * 32 + 16 + quad * 4 + 0], 0.f);
        float p5 = fmaxf(s1[1] + b1s[c * 32 + 16 + quad * 4 + 1], 0.f);
        float p6 = fmaxf(s1[2] + b1s[c * 32 + 16 + quad * 4 + 2], 0.f);
        float p7 = fmaxf(s1[3] + b1s[c * 32 + 16 + quad * 4 + 3], 0.f);

        PU pu;
        pu.wd[0] = cvt_pk_bf16(p0, p1);
        pu.wd[1] = cvt_pk_bf16(p2, p3);
        pu.wd[2] = cvt_pk_bf16(p4, p5);
        pu.wd[3] = cvt_pk_bf16(p6, p7);

        // ---- lin2: acc[ot] += P @ W2 (sigma-ordered Vt) ----
        #pragma unroll
        for (int ot = 0; ot < 32; ot++) {
            short8_t bv = *(const short8_t*)&Vt[cur][ot * 16 + n16][q8];
            acc[ot] = __builtin_amdgcn_mfma_f32_16x16x32_bf16(pu.s8, bv, acc[ot], 0, 0, 0);
        }

        // ---- write prefetched W2 into Vt[nxt] ----
        if (c < 63) {
            #pragma unroll
            for (int i = 0; i < 16; i++)
                *(ushort4*)&Vt[nxt][i * 32 + (tid >> 3)][pos] = w2r[i];
        }
        __syncthreads();   // drains W1 DMA + orders Vt across waves
    }

    // ---- epilogue: bias + store ----
    #pragma unroll
    for (int ot = 0; ot < 32; ot++) {
        float bia = b2[ot * 16 + n16];
        #pragma unroll
        for (int r = 0; r < 4; r++) {
            int ro = m0 + w * 16 + quad * 4 + r;
            Cout[(size_t)ro * DD + ot * 16 + n16] = f2b(acc[ot][r] + bia);
        }
    }
}

// ---------------- MFMA flash attention, swapped-QK in-register P (R11) ----------------
__global__ __launch_bounds__(256) void attn_wp(const u16* __restrict__ qb,
                                               const u16* __restrict__ kvb,
                                               u16* __restrict__ ob) {
    __shared__ u16 Kb[2][2048];        // fragment order, 4KB per buffer
    __shared__ u16 Vt[2][64][40];      // V^T [d][pos], stride 40 (2-way free)
    int tid = threadIdx.x;
    int w = tid >> 6, lane = tid & 63;
    int n16 = lane & 15, quad = lane >> 4, q8 = quad * 8;
    int xb, bh;
    xcd_remap(xb, bh);
    int b = bh >> 3, h = bh & 7;
    int q0 = xb * 128 + w * 32;

    short8_t aq[2][2];
    #pragma unroll
    for (int qt = 0; qt < 2; qt++) {
        const u16* qrow = qb + ((size_t)(q0 + qt * 16 + n16) * BB + b) * DD + h * DH;
        aq[qt][0] = *(const short8_t*)(qrow + q8);
        aq[qt][1] = *(const short8_t*)(qrow + 32 + q8);
    }

    const u16* kbase = kvb + (size_t)(b * HH + h) * (SS * DH);
    const u16* vbase = kvb + (size_t)KVPART + (size_t)(b * HH + h) * (SS * DH);

    // K DMA: wave w stages frag f=w (nt = w>>1, kh = w&1).
    const u16* gK = kbase + (size_t)((w >> 1) * 16 + n16) * DH + (w & 1) * 32 + q8;

    // V staging under sigma: lane owns positions {2m, 2m+1} (m = lane&15),
    // holding keys {key0, key0+1}: key0 = b2<2 ? 4a+2b2 : 16+4a+2(b2-2).
    int m = lane & 15;
    int a2 = m >> 2, b2 = m & 3;
    int key0 = (b2 < 2) ? (4 * a2 + 2 * b2) : (16 + 4 * a2 + 2 * (b2 - 2));
    int kp2 = m * 2;
    int vd = w * 16 + quad * 4;
    const u16* gV = vbase + (size_t)key0 * DH + vd;

    float lsum[2] = {0.f, 0.f};
    f32x4 Oa[2][4];
    #pragma unroll
    for (int qt = 0; qt < 2; qt++)
        #pragma unroll
        for (int ot = 0; ot < 4; ot++) Oa[qt][ot] = (f32x4){0.f, 0.f, 0.f, 0.f};

    union VU { ushort4 q; u16 h[4]; };
    union PU { u32 wd[4]; short8_t s8; };

    // ---- stage chunk 0 ----
    {
        async16(gK, &Kb[0][w * 512]);
        VU va, vb2;
        va.q  = *(const ushort4*)(gV);
        vb2.q = *(const ushort4*)(gV + DH);
        #pragma unroll
        for (int u = 0; u < 4; u++)
            *(u32*)&Vt[0][vd + u][kp2] = (u32)va.h[u] | ((u32)vb2.h[u] << 16);
    }
    __syncthreads();

    for (int c = 0; c < 16; c++) {
        int cur = c & 1, nxt = cur ^ 1;

        // ---- prefetch chunk c+1 (issue loads; consume after compute) ----
        VU va, vb2;
        if (c < 15) {
            const u16* gVc = gV + (size_t)(c + 1) * 32 * DH;
            va.q  = *(const ushort4*)(gVc);
            vb2.q = *(const ushort4*)(gVc + DH);
            async16(gK + (size_t)(c + 1) * 32 * DH, &Kb[nxt][w * 512]);
        }

        short8_t bk0 = *(const short8_t*)&Kb[cur][0 * 512 + lane * 8];
        short8_t bk1 = *(const short8_t*)&Kb[cur][1 * 512 + lane * 8];
        short8_t bk2 = *(const short8_t*)&Kb[cur][2 * 512 + lane * 8];
        short8_t bk3 = *(const short8_t*)&Kb[cur][3 * 512 + lane * 8];

        #pragma unroll
        for (int qt = 0; qt < 2; qt++) {
            // swapped QK^T: sc[nt] = K_nt * Q  -> D[key=quad*4+r][q=n16]
            f32x4 s0 = (f32x4){0.f, 0.f, 0.f, 0.f};
            s0 = __builtin_amdgcn_mfma_f32_16x16x32_bf16(bk0, aq[qt][0], s0, 0, 0, 0);
            s0 = __builtin_amdgcn_mfma_f32_16x16x32_bf16(bk1, aq[qt][1], s0, 0, 0, 0);
            f32x4 s1 = (f32x4){0.f, 0.f, 0.f, 0.f};
            s1 = __builtin_amdgcn_mfma_f32_16x16x32_bf16(bk2, aq[qt][0], s1, 0, 0, 0);
            s1 = __builtin_amdgcn_mfma_f32_16x16x32_bf16(bk3, aq[qt][1], s1, 0, 0, 0);

            // fixed-max softmax, all in registers
            float p0 = __expf(s0[0] * 0.125f - 8.0f);
            float p1 = __expf(s0[1] * 0.125f - 8.0f);
            float p2 = __expf(s0[2] * 0.125f - 8.0f);
            float p3 = __expf(s0[3] * 0.125f - 8.0f);
            float p4 = __expf(s1[0] * 0.125f - 8.0f);
            float p5 = __expf(s1[1] * 0.125f - 8.0f);
            float p6 = __expf(s1[2] * 0.125f - 8.0f);
            float p7 = __expf(s1[3] * 0.125f - 8.0f);
            lsum[qt] += ((p0 + p1) + (p2 + p3)) + ((p4 + p5) + (p6 + p7));

            PU pu;
            pu.wd[0] = cvt_pk_bf16(p0, p1);
            pu.wd[1] = cvt_pk_bf16(p2, p3);
            pu.wd[2] = cvt_pk_bf16(p4, p5);
            pu.wd[3] = cvt_pk_bf16(p6, p7);

            // O += P @ V (A = P in-register, B = V from sigma-ordered Vt)
            #pragma unroll
            for (int ot = 0; ot < 4; ot++) {
                short8_t bv = *(const short8_t*)&Vt[cur][ot * 16 + n16][q8];
                Oa[qt][ot] = __builtin_amdgcn_mfma_f32_16x16x32_bf16(pu.s8, bv, Oa[qt][ot], 0, 0, 0);
            }
        }

        // ---- write prefetched V into Vt[nxt] ----
        if (c < 15) {
            #pragma unroll
            for (int u = 0; u < 4; u++)
                *(u32*)&Vt[nxt][vd + u][kp2] = (u32)va.h[u] | ((u32)vb2.h[u] << 16);
        }
        __syncthreads();   // drains my K-DMA (vmcnt0) + orders LDS across waves
    }

    #pragma unroll
    for (int qt = 0; qt < 2; qt++) {
        // lsum[qt] is partial for q=n16 over this quad's 8 keys; sum quads
        float l = lsum[qt];
        l += __shfl_xor(l, 16, 64);
        l += __shfl_xor(l, 32, 64);
        #pragma unroll
        for (int r = 0; r < 4; r++) {
            float lq = __shfl(l, quad * 4 + r, 64);   // l for q = quad*4+r
            float inv = 1.f / lq;
            int t = q0 + qt * 16 + quad * 4 + r;
            u16* orow = ob + ((size_t)t * BB + b) * DD + h * DH + n16;
            #pragma unroll
            for (int ot = 0; ot < 4; ot++) orow[ot * 16] = f2b(Oa[qt][ot][r] * inv);
        }
    }
}

// ---------------- host ----------------
extern "C" void kernel_launch(void* const* d_in, const int* in_sizes, int n_in,
                              void* d_out, int out_size, void* d_ws, size_t ws_size,
                              hipStream_t stream) {
    const float* tgt       = (const float*)d_in[0];
    const float* memory    = (const float*)d_in[1];
    const float* queries   = (const float*)d_in[2];
    const float* wk        = (const float*)d_in[3];
    const float* in_proj_w = (const float*)d_in[4];
    const float* in_proj_b = (const float*)d_in[5];
    const float* out_proj_w= (const float*)d_in[6];
    const float* out_proj_b= (const float*)d_in[7];
    const float* lin1_w    = (const float*)d_in[8];
    const float* lin1_b    = (const float*)d_in[9];
    const float* lin2_w    = (const float*)d_in[10];
    const float* lin2_b    = (const float*)d_in[11];
    const float* ln1_g     = (const float*)d_in[12];
    const float* ln1_b     = (const float*)d_in[13];
    const float* ln2_g     = (const float*)d_in[14];
    const float* ln2_b     = (const float*)d_in[15];
    const float* ln3_g     = (const float*)d_in[16];
    const float* ln3_b     = (const float*)d_in[17];

    char* w = (char*)d_ws;
    float* qeff  = (float*)(w + 0);
    float* pbuf  = (float*)(w + 20480);
    float* mixed = (float*)(w + 872448);
    u16* y1  = (u16*)(w + 2969600);
    u16* qb  = (u16*)(w + 19746816);
    u16* kvb = (u16*)(w + 36524032);   // 8.4MB head-major KV
    u16* ob  = (u16*)(w + 44912640);
    // pre-attention residents of the ob region (dead before attn writes ob):
    u16* ipwb = (u16*)(w + 44912640);  // in_proj_w bf16 [1536*512]
    u16* memb = (u16*)(w + 46485504);  // memory bf16 [4096*512]
    // post-attention residents of the kvb region (kvb dead after attn):
    u16* opwb = (u16*)(w + 36524032);  // out_proj_w bf16 [512*512]
    u16* l1wb = (u16*)(w + 37048320);  // lin1_w bf16 [2048*512]
    u16* l2wb = (u16*)(w + 39145472);  // lin2_w bf16 [512*2048]
    u16* t1 = qb;  // out_proj result (qb dead after attention)
    u16* y2 = ob;  // LN2 out (ob = attn out, dead after out_proj)
    u16* fb = y1;  // FFN out (y1 dead after LN2)

    // ---- pre-attention conversions (memory + in_proj_w, fused) ----
    cvt2_kernel<<<2816, 256, 0, stream>>>(memory, in_proj_w, memb, ipwb);

    // ---- QA block ----
    qeff_kernel<<<1, 512, 0, stream>>>(queries, qeff);
    p_kernel<<<BB * (TT / 4), 256, 0, stream>>>(tgt, qeff, pbuf);
    winmix_kernel<<<BB * NW, 256, 0, stream>>>(pbuf, wk, tgt, mixed);
    ln_qa_kernel<<<(TT * BB) / 4, 256, 0, stream>>>(tgt, mixed, ln1_g, ln1_b, y1);

    // ---- MHA ----
    gemm_lds<0, 4, 0><<<dim3(DD / 128, (TT * BB) / 128), 256, 0, stream>>>(y1, ipwb, in_proj_b, qb, TT * BB, DD, DD);
    gemm_np<0, 1><<<dim3(1024 / 64, (SS * BB) / 64), 256, 0, stream>>>(memb, ipwb + (size_t)DD * DD, in_proj_b + DD, kvb, SS * BB, 1024, DD);
    attn_wp<<<dim3(TT / 128, BB * HH), 256, 0, stream>>>(qb, kvb, ob);
    // kvb dead; convert remaining weights into its region (fused)
    cvt3_kernel<<<2304, 256, 0, stream>>>(out_proj_w, lin1_w, lin2_w, opwb, l1wb, l2wb);
    gemm_lds<0, 4, 0><<<dim3(DD / 128, (TT * BB) / 128), 256, 0, stream>>>(ob, opwb, out_proj_b, t1, TT * BB, DD, DD);
    ln_rows_kernel<u16><<<(TT * BB) / 4, 256, 0, stream>>>(y1, t1, ln2_g, ln2_b, y2);

    // ---- fused FFN (single dispatch; hidden never leaves registers) ----
    ffn_fused<<<(TT * BB) / 64, 256, 0, stream>>>(y2, l1wb, lin1_b, l2wb, lin2_b, fb);
    ln_rows_kernel<float><<<(TT * BB) / 4, 256, 0, stream>>>(y2, fb, ln3_g, ln3_b, (float*)d_out);
}